// Round 3
// baseline (1044.284 us; speedup 1.0000x reference)
//
#include <hip/hip_runtime.h>
#include <hip/hip_bf16.h>

// GraphSAGE net on MI355X: bf16 MFMA GEMMs + bf16 gather aggregation.
// N=50000, E=800000/layer, D=128, H=256, O=3.
//
// CSR build is a bucketed counting sort (nodes fit in u16 -> edge packs in u32):
//   hist -> 3-kernel parallel scan -> bin (bucket append, dense writes)
//   -> fill2 (bucket-local CSR placement, L2-dense) ; csr stored as u16.

#define DD 128
#define SB 8              // 2^8 = 256 nodes per bucket
typedef unsigned short u16;
typedef __attribute__((ext_vector_type(8))) short short8;
typedef __attribute__((ext_vector_type(4))) float f32x4;

__device__ inline u16 f2bf(float f) {
    __hip_bfloat16 h = __float2bfloat16(f);
    u16 u;
    __builtin_memcpy(&u, &h, 2);
    return u;
}
__device__ inline float bf_lo(unsigned u) { union { unsigned x; float f; } c; c.x = u << 16; return c.f; }
__device__ inline float bf_hi(unsigned u) { union { unsigned x; float f; } c; c.x = u & 0xffff0000u; return c.f; }

// ---------------- fused fp32 -> bf16 cast ----------------
struct CastJobs {
    const float4* src[7];
    uint2* dst[7];
    int qstart[8];
};
__global__ __launch_bounds__(256) void cast_kernel(CastJobs jb) {
    int q = blockIdx.x * 256 + threadIdx.x;
    if (q >= jb.qstart[7]) return;
    int i = 0;
#pragma unroll
    for (int k = 1; k < 7; ++k) if (q >= jb.qstart[k]) i = k;
    int local = q - jb.qstart[i];
    float4 v = jb.src[i][local];
    unsigned lo = (unsigned)f2bf(v.x) | ((unsigned)f2bf(v.y) << 16);
    unsigned hi = (unsigned)f2bf(v.z) | ((unsigned)f2bf(v.w) << 16);
    jb.dst[i][local] = make_uint2(lo, hi);
}

// ---------------- CSR build ----------------
__global__ __launch_bounds__(256) void init_kernel(int* __restrict__ d0, int* __restrict__ f0,
                                                   int* __restrict__ d1, int* __restrict__ f1, int n) {
    int i = blockIdx.x * 256 + threadIdx.x;
    if (i < n) { d0[i] = 0; f0[i] = 0; d1[i] = 0; f1[i] = 0; }
}

__global__ __launch_bounds__(256) void hist_kernel(const int* __restrict__ dst0, int* __restrict__ deg0,
                                                   const int* __restrict__ dst1, int* __restrict__ deg1,
                                                   int e0, int e1) {
    int e = blockIdx.x * 256 + threadIdx.x;
    if (e < e0) atomicAdd(&deg0[dst0[e]], 1);
    if (e < e1) atomicAdd(&deg1[dst1[e]], 1);
}

// scan stage 1: per-256-block exclusive scan, emit block sums. grid = 2*nb.
__global__ __launch_bounds__(256) void scan_k1(const int* __restrict__ deg0, int* __restrict__ rp0, int* __restrict__ bsum0,
                                               const int* __restrict__ deg1, int* __restrict__ rp1, int* __restrict__ bsum1,
                                               int n, int nb) {
    int arr = blockIdx.x >= nb;
    int blk = blockIdx.x - (arr ? nb : 0);
    const int* deg = arr ? deg1 : deg0;
    int* rp = arr ? rp1 : rp0;
    int* bs = arr ? bsum1 : bsum0;
    __shared__ int s[256];
    int t = threadIdx.x, i = blk * 256 + t;
    int v = (i < n) ? deg[i] : 0;
    s[t] = v;
    __syncthreads();
    for (int off = 1; off < 256; off <<= 1) {
        int u = (t >= off) ? s[t - off] : 0;
        __syncthreads();
        s[t] += u;
        __syncthreads();
    }
    if (i < n) rp[i] = s[t] - v;
    if (t == 255) bs[blk] = s[255];
}

// scan stage 2: exclusive scan of nb block sums (nb <= 256). grid = 2.
__global__ __launch_bounds__(256) void scan_k2(int* __restrict__ bsum0, int* __restrict__ bsum1, int nb) {
    int* bs = blockIdx.x ? bsum1 : bsum0;
    __shared__ int s[256];
    int t = threadIdx.x;
    int v = (t < nb) ? bs[t] : 0;
    s[t] = v;
    __syncthreads();
    for (int off = 1; off < 256; off <<= 1) {
        int u = (t >= off) ? s[t - off] : 0;
        __syncthreads();
        s[t] += u;
        __syncthreads();
    }
    if (t < nb) bs[t] = s[t] - v;
}

// scan stage 3: add block offsets; init bucket fill counters to bucket base; rp[n] = E.
__global__ __launch_bounds__(256) void scan_k3(int* __restrict__ rp0, const int* __restrict__ bsum0, int* __restrict__ bfill0, int e0,
                                               int* __restrict__ rp1, const int* __restrict__ bsum1, int* __restrict__ bfill1, int e1,
                                               int n, int nb) {
    int arr = blockIdx.x >= nb;
    int blk = blockIdx.x - (arr ? nb : 0);
    int* rp = arr ? rp1 : rp0;
    const int* bs = arr ? bsum1 : bsum0;
    int* bf = arr ? bfill1 : bfill0;
    int t = threadIdx.x, i = blk * 256 + t;
    if (i < n) {
        int v = rp[i] + bs[blk];
        rp[i] = v;
        if (t == 0) bf[blk] = v;       // bucket blk base = rp[blk*256]
    }
    if (i == 0) rp[n] = arr ? e1 : e0;
}

// bin: append packed (dst<<16|src) to dst's bucket (bucket regions CSR-aligned, dense writes).
__global__ __launch_bounds__(256) void bin_kernel(
    const int* __restrict__ src0, const int* __restrict__ dst0, int* __restrict__ bfill0, unsigned* __restrict__ binned0,
    const int* __restrict__ src1, const int* __restrict__ dst1, int* __restrict__ bfill1, unsigned* __restrict__ binned1,
    int e0, int e1) {
    int e = blockIdx.x * 256 + threadIdx.x;
    if (e < e0) {
        int d = dst0[e];
        int p = atomicAdd(&bfill0[d >> SB], 1);
        binned0[p] = ((unsigned)d << 16) | (unsigned)src0[e];
    }
    if (e < e1) {
        int d = dst1[e];
        int p = atomicAdd(&bfill1[d >> SB], 1);
        binned1[p] = ((unsigned)d << 16) | (unsigned)src1[e];
    }
}

// fill2: place src into csr[rp[dst]+pos]; writes stay in the bucket-local (L2-hot) region.
__global__ __launch_bounds__(256) void fill2_kernel(
    const unsigned* __restrict__ binned0, const int* __restrict__ rp0, int* __restrict__ f0, u16* __restrict__ csr0,
    const unsigned* __restrict__ binned1, const int* __restrict__ rp1, int* __restrict__ f1, u16* __restrict__ csr1,
    int e0, int e1) {
    int e = blockIdx.x * 256 + threadIdx.x;
    if (e < e0) {
        unsigned pk = binned0[e];
        int d = pk >> 16;
        int p = atomicAdd(&f0[d], 1);
        csr0[rp0[d] + p] = (u16)(pk & 0xffffu);
    }
    if (e < e1) {
        unsigned pk = binned1[e];
        int d = pk >> 16;
        int p = atomicAdd(&f1[d], 1);
        csr1[rp1[d] + p] = (u16)(pk & 0xffffu);
    }
}

// ---------------- mean aggregation: bf16 gather, fp32 accum ----------------
// 16 lanes per node, 16B (8 bf16) per lane per neighbor row.
__global__ __launch_bounds__(256) void agg_mean_bf16(const u16* __restrict__ X,
                                                     const u16* __restrict__ csr,
                                                     const int* __restrict__ rp,
                                                     u16* __restrict__ out, int n) {
    int g = (blockIdx.x * 256 + threadIdx.x) >> 4;
    int lane = threadIdx.x & 15;
    if (g >= n) return;
    int start = rp[g];
    int end = rp[g + 1];
    int d = end - start;
    const uint4* X4 = (const uint4*)X;
    float acc[8] = {0.f, 0.f, 0.f, 0.f, 0.f, 0.f, 0.f, 0.f};
    int e = start;
    for (; e + 1 < end; e += 2) {
        int s0 = csr[e], s1 = csr[e + 1];
        uint4 v0 = X4[(size_t)s0 * 16 + lane];
        uint4 v1 = X4[(size_t)s1 * 16 + lane];
        acc[0] += bf_lo(v0.x) + bf_lo(v1.x); acc[1] += bf_hi(v0.x) + bf_hi(v1.x);
        acc[2] += bf_lo(v0.y) + bf_lo(v1.y); acc[3] += bf_hi(v0.y) + bf_hi(v1.y);
        acc[4] += bf_lo(v0.z) + bf_lo(v1.z); acc[5] += bf_hi(v0.z) + bf_hi(v1.z);
        acc[6] += bf_lo(v0.w) + bf_lo(v1.w); acc[7] += bf_hi(v0.w) + bf_hi(v1.w);
    }
    if (e < end) {
        int s0 = csr[e];
        uint4 v0 = X4[(size_t)s0 * 16 + lane];
        acc[0] += bf_lo(v0.x); acc[1] += bf_hi(v0.x);
        acc[2] += bf_lo(v0.y); acc[3] += bf_hi(v0.y);
        acc[4] += bf_lo(v0.z); acc[5] += bf_hi(v0.z);
        acc[6] += bf_lo(v0.w); acc[7] += bf_hi(v0.w);
    }
    float scale = 1.0f / (float)max(d, 1);
    uint4 r;
    r.x = (unsigned)f2bf(acc[0] * scale) | ((unsigned)f2bf(acc[1] * scale) << 16);
    r.y = (unsigned)f2bf(acc[2] * scale) | ((unsigned)f2bf(acc[3] * scale) << 16);
    r.z = (unsigned)f2bf(acc[4] * scale) | ((unsigned)f2bf(acc[5] * scale) << 16);
    r.w = (unsigned)f2bf(acc[6] * scale) | ((unsigned)f2bf(acc[7] * scale) << 16);
    ((uint4*)out)[(size_t)g * 16 + lane] = r;
}

// ---------------- MFMA GEMM: C = sum_p A_p @ W_p.T + bias [relu], bf16 in/out ----------------
// BM=64, BN=128, whole K=128 staged. 256 thr = 4 waves, 16x16x32 MFMA.
template <bool RELU>
__global__ __launch_bounds__(256) void mfma_gemm(
    const u16* __restrict__ A0, const u16* __restrict__ W0,
    const u16* __restrict__ A1, const u16* __restrict__ W1,
    const u16* __restrict__ A2, const u16* __restrict__ W2,
    int npair,
    const float* __restrict__ bias0, const float* __restrict__ bias1,
    u16* __restrict__ C, int M, int NC, int mB) {
    __shared__ u16 As[64 * 136];
    __shared__ u16 Bs[128 * 136];
    const int t = threadIdx.x;
    const int rowBase = (blockIdx.x % mB) * 64;
    const int colBase = (blockIdx.x / mB) * 128;
    const int w = t >> 6, lane = t & 63, r = lane & 15, half = lane >> 4;

    const u16* Ap[3] = {A0, A1, A2};
    const u16* Wp[3] = {W0, W1, W2};

    f32x4 acc[8];
#pragma unroll
    for (int i = 0; i < 8; ++i) acc[i] = (f32x4){0.f, 0.f, 0.f, 0.f};

    for (int p = 0; p < npair; ++p) {
        if (p) __syncthreads();
        const uint4* Ag = (const uint4*)Ap[p];
        const uint4* Wg = (const uint4*)Wp[p];
#pragma unroll
        for (int i = 0; i < 4; ++i) {
            int id = t + 256 * i, row = id >> 4, cc = id & 15;
            int gr = rowBase + row;
            uint4 v = make_uint4(0u, 0u, 0u, 0u);
            if (gr < M) v = Ag[(size_t)gr * 16 + cc];
            *(uint4*)&As[row * 136 + cc * 8] = v;
        }
#pragma unroll
        for (int i = 0; i < 8; ++i) {
            int id = t + 256 * i, row = id >> 4, cc = id & 15;
            *(uint4*)&Bs[row * 136 + cc * 8] = Wg[(size_t)(colBase + row) * 16 + cc];
        }
        __syncthreads();
        const u16* aB = &As[(w * 16 + r) * 136 + half * 8];
        const u16* bB = &Bs[r * 136 + half * 8];
#pragma unroll
        for (int kk = 0; kk < 4; ++kk) {
            short8 af = *(const short8*)(aB + kk * 32);
#pragma unroll
            for (int ct = 0; ct < 8; ++ct) {
                short8 bf = *(const short8*)(bB + ct * (16 * 136) + kk * 32);
                acc[ct] = __builtin_amdgcn_mfma_f32_16x16x32_bf16(af, bf, acc[ct], 0, 0, 0);
            }
        }
    }

#pragma unroll
    for (int ct = 0; ct < 8; ++ct) {
        int col = colBase + ct * 16 + r;
        float bv = bias0[col];
        if (bias1) bv += bias1[col];
#pragma unroll
        for (int reg = 0; reg < 4; ++reg) {
            int row = rowBase + w * 16 + half * 4 + reg;
            if (row < M) {
                float v = acc[ct][reg] + bv;
                if (RELU) v = fmaxf(v, 0.f);
                C[(size_t)row * NC + col] = f2bf(v);
            }
        }
    }
}

// ---------------- output: out[N,3] = h4(bf16) @ W2.T(fp32) + b2, one wave/row ----------------
__global__ __launch_bounds__(256) void out_kernel(const u16* __restrict__ h4,
                                                  const float* __restrict__ W2,
                                                  const float* __restrict__ b2,
                                                  float* __restrict__ out, int n) {
    int w = (blockIdx.x * 256 + threadIdx.x) >> 6;
    int lane = threadIdx.x & 63;
    if (w >= n) return;
    uint2 hv = ((const uint2*)h4)[(size_t)w * 64 + lane];
    float h0 = bf_lo(hv.x), h1 = bf_hi(hv.x), h2 = bf_lo(hv.y), h3 = bf_hi(hv.y);
    float4 w0 = ((const float4*)W2)[0 * 64 + lane];
    float4 w1 = ((const float4*)W2)[1 * 64 + lane];
    float4 w2 = ((const float4*)W2)[2 * 64 + lane];
    float p0 = h0 * w0.x + h1 * w0.y + h2 * w0.z + h3 * w0.w;
    float p1 = h0 * w1.x + h1 * w1.y + h2 * w1.z + h3 * w1.w;
    float p2 = h0 * w2.x + h1 * w2.y + h2 * w2.z + h3 * w2.w;
#pragma unroll
    for (int off = 32; off > 0; off >>= 1) {
        p0 += __shfl_xor(p0, off);
        p1 += __shfl_xor(p1, off);
        p2 += __shfl_xor(p2, off);
    }
    if (lane == 0) {
        out[(size_t)w * 3 + 0] = p0 + b2[0];
        out[(size_t)w * 3 + 1] = p1 + b2[1];
        out[(size_t)w * 3 + 2] = p2 + b2[2];
    }
}

extern "C" void kernel_launch(void* const* d_in, const int* in_sizes, int n_in,
                              void* d_out, int out_size, void* d_ws, size_t ws_size,
                              hipStream_t stream) {
    const float* x   = (const float*)d_in[0];
    const int*   ei0 = (const int*)d_in[1];
    const int*   ei1 = (const int*)d_in[2];
    const float* Wl1 = (const float*)d_in[3];
    const float* bl1 = (const float*)d_in[4];
    const float* Wr1 = (const float*)d_in[5];
    const float* Wl2 = (const float*)d_in[6];
    const float* bl2 = (const float*)d_in[7];
    const float* Wr2 = (const float*)d_in[8];
    const float* Wsk = (const float*)d_in[9];
    const float* bsk = (const float*)d_in[10];
    const float* W1  = (const float*)d_in[11];
    const float* b1  = (const float*)d_in[12];
    const float* W2  = (const float*)d_in[13];
    const float* b2  = (const float*)d_in[14];
    float* out = (float*)d_out;

    const int N  = in_sizes[0] / DD;   // 50000
    const int E0 = in_sizes[1] / 2;    // 800000
    const int E1 = in_sizes[2] / 2;
    const int H  = in_sizes[12];       // 256

    const int* src0 = ei0;      const int* dst0 = ei0 + E0;
    const int* src1 = ei1;      const int* dst1 = ei1 + E1;

    // workspace carve (256B aligned)
    char* wp = (char*)d_ws;
    auto carve = [&](size_t bytes) { char* p = wp; wp += (bytes + 255) & ~(size_t)255; return p; };
    u16* xh   = (u16*)carve((size_t)N * DD * 2);
    u16* aggh = (u16*)carve((size_t)N * DD * 2);
    u16* h1h  = (u16*)carve((size_t)N * DD * 2);
    u16* h3h  = (u16*)carve((size_t)N * DD * 2);
    u16* h4h  = (u16*)carve((size_t)N * H * 2);
    u16* wl1h = (u16*)carve((size_t)DD * DD * 2);
    u16* wr1h = (u16*)carve((size_t)DD * DD * 2);
    u16* wl2h = (u16*)carve((size_t)DD * DD * 2);
    u16* wr2h = (u16*)carve((size_t)DD * DD * 2);
    u16* wsh  = (u16*)carve((size_t)DD * DD * 2);
    u16* w1h  = (u16*)carve((size_t)H * DD * 2);
    int* deg0 = (int*)carve((size_t)N * 4);
    int* rp0  = (int*)carve((size_t)(N + 1) * 4);
    int* f0   = (int*)carve((size_t)N * 4);
    int* deg1 = (int*)carve((size_t)N * 4);
    int* rp1  = (int*)carve((size_t)(N + 1) * 4);
    int* f1   = (int*)carve((size_t)N * 4);
    u16* csr0 = (u16*)carve((size_t)E0 * 2);
    u16* csr1 = (u16*)carve((size_t)E1 * 2);
    unsigned* binned0 = (unsigned*)carve((size_t)E0 * 4);
    unsigned* binned1 = (unsigned*)carve((size_t)E1 * 4);
    const int nb = (N + 255) >> 8;     // 196 scan blocks == dst buckets
    int* bsum0  = (int*)carve((size_t)nb * 4);
    int* bsum1  = (int*)carve((size_t)nb * 4);
    int* bfill0 = (int*)carve((size_t)nb * 4);
    int* bfill1 = (int*)carve((size_t)nb * 4);

    // fused cast: x + 6 weight matrices
    CastJobs jb;
    const float* srcs[7] = {x, Wl1, Wr1, Wl2, Wr2, Wsk, W1};
    u16* dsts[7]         = {xh, wl1h, wr1h, wl2h, wr2h, wsh, w1h};
    int  cnts[7] = {N * DD, DD * DD, DD * DD, DD * DD, DD * DD, DD * DD, H * DD};
    int q = 0;
    for (int i = 0; i < 7; ++i) {
        jb.src[i] = (const float4*)srcs[i];
        jb.dst[i] = (uint2*)dsts[i];
        jb.qstart[i] = q;
        q += cnts[i] / 4;
    }
    jb.qstart[7] = q;

    const int gN   = (N + 255) / 256;
    const int Emax = (E0 > E1) ? E0 : E1;
    const int gE   = (Emax + 255) / 256;
    const int gAgg = (N * 16 + 255) / 256;
    const int mB   = (N + 63) / 64;    // 782

    cast_kernel<<<(q + 255) / 256, 256, 0, stream>>>(jb);
    init_kernel<<<gN, 256, 0, stream>>>(deg0, f0, deg1, f1, N);
    hist_kernel<<<gE, 256, 0, stream>>>(dst0, deg0, dst1, deg1, E0, E1);
    scan_k1<<<2 * nb, 256, 0, stream>>>(deg0, rp0, bsum0, deg1, rp1, bsum1, N, nb);
    scan_k2<<<2, 256, 0, stream>>>(bsum0, bsum1, nb);
    scan_k3<<<2 * nb, 256, 0, stream>>>(rp0, bsum0, bfill0, E0, rp1, bsum1, bfill1, E1, N, nb);
    bin_kernel<<<gE, 256, 0, stream>>>(src0, dst0, bfill0, binned0,
                                       src1, dst1, bfill1, binned1, E0, E1);
    fill2_kernel<<<gE, 256, 0, stream>>>(binned0, rp0, f0, csr0,
                                         binned1, rp1, f1, csr1, E0, E1);

    // layer 1
    agg_mean_bf16<<<gAgg, 256, 0, stream>>>(xh, csr0, rp0, aggh, N);
    mfma_gemm<false><<<mB, 256, 0, stream>>>(
        aggh, wl1h, xh, wr1h, nullptr, nullptr, 2, bl1, nullptr, h1h, N, DD, mB);

    // layer 2 + skip
    agg_mean_bf16<<<gAgg, 256, 0, stream>>>(h1h, csr1, rp1, aggh, N);
    mfma_gemm<false><<<mB, 256, 0, stream>>>(
        aggh, wl2h, h1h, wr2h, xh, wsh, 3, bl2, bsk, h3h, N, DD, mB);

    // MLP hidden (NC=256 -> 2 column blocks)
    mfma_gemm<true><<<mB * (H / 128), 256, 0, stream>>>(
        h3h, w1h, nullptr, nullptr, nullptr, nullptr, 1, b1, nullptr, h4h, N, H, mB);

    // output layer
    const int gOut = (N * 64 + 255) / 256;
    out_kernel<<<gOut, 256, 0, stream>>>(h4h, W2, b2, out, N);
}

// Round 4
// 362.689 us; speedup vs baseline: 2.8793x; 2.8793x over previous
//
#include <hip/hip_runtime.h>
#include <hip/hip_bf16.h>

// GraphSAGE net on MI355X: bf16 MFMA GEMMs + bf16 gather aggregation.
// N=50000, E=800000/layer, D=128, H=256, O=3.
//
// CSR build = deterministic partitioned counting sort, ZERO global atomics
// in the scatter phases (round-3 lesson: same-address device atomics ~85ns):
//   hist (per-node degree, atomics spread over 50k addrs - fine)
//   -> 3-kernel rp scan
//   -> hist1[bucket][partition] via LDS histograms
//   -> offs: per-bucket scan over partitions (+ rp[b<<8] base)
//   -> scatter1: LDS bump counters, plain stores -> bucket-contiguous binned
//   -> place: per-bucket block, LDS per-node counters, dense u16 CSR writes

#define DD 128
#define SB 8               // 256 nodes per bucket
#define CH 4096            // edges per partition chunk
typedef unsigned short u16;
typedef __attribute__((ext_vector_type(8))) short short8;
typedef __attribute__((ext_vector_type(4))) float f32x4;

__device__ inline u16 f2bf(float f) {
    __hip_bfloat16 h = __float2bfloat16(f);
    u16 u;
    __builtin_memcpy(&u, &h, 2);
    return u;
}
__device__ inline float bf_lo(unsigned u) { union { unsigned x; float f; } c; c.x = u << 16; return c.f; }
__device__ inline float bf_hi(unsigned u) { union { unsigned x; float f; } c; c.x = u & 0xffff0000u; return c.f; }

// ---------------- fused fp32 -> bf16 cast ----------------
struct CastJobs {
    const float4* src[7];
    uint2* dst[7];
    int qstart[8];
};
__global__ __launch_bounds__(256) void cast_kernel(CastJobs jb) {
    int q = blockIdx.x * 256 + threadIdx.x;
    if (q >= jb.qstart[7]) return;
    int i = 0;
#pragma unroll
    for (int k = 1; k < 7; ++k) if (q >= jb.qstart[k]) i = k;
    int local = q - jb.qstart[i];
    float4 v = jb.src[i][local];
    unsigned lo = (unsigned)f2bf(v.x) | ((unsigned)f2bf(v.y) << 16);
    unsigned hi = (unsigned)f2bf(v.z) | ((unsigned)f2bf(v.w) << 16);
    jb.dst[i][local] = make_uint2(lo, hi);
}

// ---------------- CSR build ----------------
__global__ __launch_bounds__(256) void init_kernel(int* __restrict__ d0, int* __restrict__ d1, int n) {
    int i = blockIdx.x * 256 + threadIdx.x;
    if (i < n) { d0[i] = 0; d1[i] = 0; }
}

__global__ __launch_bounds__(256) void hist_kernel(const int* __restrict__ dst0, int* __restrict__ deg0,
                                                   const int* __restrict__ dst1, int* __restrict__ deg1,
                                                   int e0, int e1) {
    int e = blockIdx.x * 256 + threadIdx.x;
    if (e < e0) atomicAdd(&deg0[dst0[e]], 1);
    if (e < e1) atomicAdd(&deg1[dst1[e]], 1);
}

// rp scan stage 1: per-256-block exclusive scan, emit block sums. grid = 2*nb.
__global__ __launch_bounds__(256) void scan_k1(const int* __restrict__ deg0, int* __restrict__ rp0, int* __restrict__ bsum0,
                                               const int* __restrict__ deg1, int* __restrict__ rp1, int* __restrict__ bsum1,
                                               int n, int nb) {
    int arr = blockIdx.x >= nb;
    int blk = blockIdx.x - (arr ? nb : 0);
    const int* deg = arr ? deg1 : deg0;
    int* rp = arr ? rp1 : rp0;
    int* bs = arr ? bsum1 : bsum0;
    __shared__ int s[256];
    int t = threadIdx.x, i = blk * 256 + t;
    int v = (i < n) ? deg[i] : 0;
    s[t] = v;
    __syncthreads();
    for (int off = 1; off < 256; off <<= 1) {
        int u = (t >= off) ? s[t - off] : 0;
        __syncthreads();
        s[t] += u;
        __syncthreads();
    }
    if (i < n) rp[i] = s[t] - v;
    if (t == 255) bs[blk] = s[255];
}

// rp scan stage 2: exclusive scan of nb block sums (nb <= 256). grid = 2.
__global__ __launch_bounds__(256) void scan_k2(int* __restrict__ bsum0, int* __restrict__ bsum1, int nb) {
    int* bs = blockIdx.x ? bsum1 : bsum0;
    __shared__ int s[256];
    int t = threadIdx.x;
    int v = (t < nb) ? bs[t] : 0;
    s[t] = v;
    __syncthreads();
    for (int off = 1; off < 256; off <<= 1) {
        int u = (t >= off) ? s[t - off] : 0;
        __syncthreads();
        s[t] += u;
        __syncthreads();
    }
    if (t < nb) bs[t] = s[t] - v;
}

// rp scan stage 3: add block offsets; rp[n] = E.
__global__ __launch_bounds__(256) void scan_k3(int* __restrict__ rp0, const int* __restrict__ bsum0, int e0,
                                               int* __restrict__ rp1, const int* __restrict__ bsum1, int e1,
                                               int n, int nb) {
    int arr = blockIdx.x >= nb;
    int blk = blockIdx.x - (arr ? nb : 0);
    int* rp = arr ? rp1 : rp0;
    const int* bs = arr ? bsum1 : bsum0;
    int t = threadIdx.x, i = blk * 256 + t;
    if (i < n) rp[i] += bs[blk];
    if (i == 0) rp[n] = arr ? e1 : e0;
}

// hist1: per-(bucket,partition) counts via LDS histogram. grid (P, 2).
__global__ __launch_bounds__(256) void hist1_kernel(const int* __restrict__ dst0, int* __restrict__ h0,
                                                    const int* __restrict__ dst1, int* __restrict__ h1,
                                                    int e0, int e1, int nb, int P) {
    int arr = blockIdx.y;
    const int* dst = arr ? dst1 : dst0;
    int* hist = arr ? h1 : h0;
    int e = arr ? e1 : e0;
    __shared__ int h[256];
    int t = threadIdx.x;
    h[t] = 0;
    __syncthreads();
    int base = blockIdx.x * CH;
    int hi = min(base + CH, e);
    for (int i = base + t; i < hi; i += 256) atomicAdd(&h[dst[i] >> SB], 1);
    __syncthreads();
    if (t < nb) hist[t * P + blockIdx.x] = h[t];   // [bucket][partition]
}

// offs: exclusive scan over partitions per bucket, + rp[b<<8] base. In-place. grid (nb, 2).
__global__ __launch_bounds__(256) void offs_kernel(int* __restrict__ h0, const int* __restrict__ rp0,
                                                   int* __restrict__ h1, const int* __restrict__ rp1,
                                                   int P) {
    int arr = blockIdx.y;
    int* hist = arr ? h1 : h0;
    const int* rp = arr ? rp1 : rp0;
    int b = blockIdx.x;
    __shared__ int s[256];
    int t = threadIdx.x;
    int v = (t < P) ? hist[b * P + t] : 0;
    s[t] = v;
    __syncthreads();
    for (int off = 1; off < 256; off <<= 1) {
        int u = (t >= off) ? s[t - off] : 0;
        __syncthreads();
        s[t] += u;
        __syncthreads();
    }
    if (t < P) hist[b * P + t] = s[t] - v + rp[b << SB];
}

// scatter1: chunk p writes its edges to bucket-contiguous binned via LDS bump counters.
// Plain stores only (no global atomics). grid (P, 2).
__global__ __launch_bounds__(256) void scatter1_kernel(
    const int* __restrict__ src0, const int* __restrict__ dst0, const int* __restrict__ h0, unsigned* __restrict__ binned0,
    const int* __restrict__ src1, const int* __restrict__ dst1, const int* __restrict__ h1, unsigned* __restrict__ binned1,
    int e0, int e1, int nb, int P) {
    int arr = blockIdx.y;
    const int* src = arr ? src1 : src0;
    const int* dst = arr ? dst1 : dst0;
    const int* hist = arr ? h1 : h0;
    unsigned* binned = arr ? binned1 : binned0;
    int e = arr ? e1 : e0;
    int p = blockIdx.x;
    __shared__ int cnt[256];
    int t = threadIdx.x;
    if (t < nb) cnt[t] = hist[t * P + p];
    __syncthreads();
    int base = p * CH;
    int hi = min(base + CH, e);
    for (int i = base + t; i < hi; i += 256) {
        int d = dst[i];
        int pos = atomicAdd(&cnt[d >> SB], 1);        // LDS atomic
        binned[pos] = ((unsigned)d << 16) | (unsigned)src[i];
    }
}

// place: one block per bucket; dense u16 CSR writes into block-exclusive region. grid (nb, 2).
__global__ __launch_bounds__(256) void place_kernel(
    const unsigned* __restrict__ binned0, const int* __restrict__ rp0, u16* __restrict__ csr0,
    const unsigned* __restrict__ binned1, const int* __restrict__ rp1, u16* __restrict__ csr1,
    int n, int nb) {
    int arr = blockIdx.y;
    const unsigned* binned = arr ? binned1 : binned0;
    const int* rp = arr ? rp1 : rp0;
    u16* csr = arr ? csr1 : csr0;
    int b = blockIdx.x;
    __shared__ int rpl[257];
    __shared__ int cnt[256];
    int t = threadIdx.x;
    int node0 = b << SB;
    rpl[t] = rp[min(node0 + t, n)];
    if (t == 0) rpl[256] = rp[min(node0 + 256, n)];
    cnt[t] = 0;
    __syncthreads();
    int lo = rpl[0], hi = rpl[256];
    for (int i = lo + t; i < hi; i += 256) {
        unsigned pk = binned[i];
        int ld = (pk >> 16) & 255;
        int pos = atomicAdd(&cnt[ld], 1);             // LDS atomic
        csr[rpl[ld] + pos] = (u16)(pk & 0xffffu);
    }
}

// ---------------- mean aggregation: bf16 gather, fp32 accum ----------------
__global__ __launch_bounds__(256) void agg_mean_bf16(const u16* __restrict__ X,
                                                     const u16* __restrict__ csr,
                                                     const int* __restrict__ rp,
                                                     u16* __restrict__ out, int n) {
    int g = (blockIdx.x * 256 + threadIdx.x) >> 4;
    int lane = threadIdx.x & 15;
    if (g >= n) return;
    int start = rp[g];
    int end = rp[g + 1];
    int d = end - start;
    const uint4* X4 = (const uint4*)X;
    float acc[8] = {0.f, 0.f, 0.f, 0.f, 0.f, 0.f, 0.f, 0.f};
    int e = start;
    for (; e + 1 < end; e += 2) {
        int s0 = csr[e], s1 = csr[e + 1];
        uint4 v0 = X4[(size_t)s0 * 16 + lane];
        uint4 v1 = X4[(size_t)s1 * 16 + lane];
        acc[0] += bf_lo(v0.x) + bf_lo(v1.x); acc[1] += bf_hi(v0.x) + bf_hi(v1.x);
        acc[2] += bf_lo(v0.y) + bf_lo(v1.y); acc[3] += bf_hi(v0.y) + bf_hi(v1.y);
        acc[4] += bf_lo(v0.z) + bf_lo(v1.z); acc[5] += bf_hi(v0.z) + bf_hi(v1.z);
        acc[6] += bf_lo(v0.w) + bf_lo(v1.w); acc[7] += bf_hi(v0.w) + bf_hi(v1.w);
    }
    if (e < end) {
        int s0 = csr[e];
        uint4 v0 = X4[(size_t)s0 * 16 + lane];
        acc[0] += bf_lo(v0.x); acc[1] += bf_hi(v0.x);
        acc[2] += bf_lo(v0.y); acc[3] += bf_hi(v0.y);
        acc[4] += bf_lo(v0.z); acc[5] += bf_hi(v0.z);
        acc[6] += bf_lo(v0.w); acc[7] += bf_hi(v0.w);
    }
    float scale = 1.0f / (float)max(d, 1);
    uint4 r;
    r.x = (unsigned)f2bf(acc[0] * scale) | ((unsigned)f2bf(acc[1] * scale) << 16);
    r.y = (unsigned)f2bf(acc[2] * scale) | ((unsigned)f2bf(acc[3] * scale) << 16);
    r.z = (unsigned)f2bf(acc[4] * scale) | ((unsigned)f2bf(acc[5] * scale) << 16);
    r.w = (unsigned)f2bf(acc[6] * scale) | ((unsigned)f2bf(acc[7] * scale) << 16);
    ((uint4*)out)[(size_t)g * 16 + lane] = r;
}

// ---------------- MFMA GEMM: C = sum_p A_p @ W_p.T + bias [relu], bf16 in/out ----------------
template <bool RELU>
__global__ __launch_bounds__(256) void mfma_gemm(
    const u16* __restrict__ A0, const u16* __restrict__ W0,
    const u16* __restrict__ A1, const u16* __restrict__ W1,
    const u16* __restrict__ A2, const u16* __restrict__ W2,
    int npair,
    const float* __restrict__ bias0, const float* __restrict__ bias1,
    u16* __restrict__ C, int M, int NC, int mB) {
    __shared__ u16 As[64 * 136];
    __shared__ u16 Bs[128 * 136];
    const int t = threadIdx.x;
    const int rowBase = (blockIdx.x % mB) * 64;
    const int colBase = (blockIdx.x / mB) * 128;
    const int w = t >> 6, lane = t & 63, r = lane & 15, half = lane >> 4;

    const u16* Ap[3] = {A0, A1, A2};
    const u16* Wp[3] = {W0, W1, W2};

    f32x4 acc[8];
#pragma unroll
    for (int i = 0; i < 8; ++i) acc[i] = (f32x4){0.f, 0.f, 0.f, 0.f};

    for (int p = 0; p < npair; ++p) {
        if (p) __syncthreads();
        const uint4* Ag = (const uint4*)Ap[p];
        const uint4* Wg = (const uint4*)Wp[p];
#pragma unroll
        for (int i = 0; i < 4; ++i) {
            int id = t + 256 * i, row = id >> 4, cc = id & 15;
            int gr = rowBase + row;
            uint4 v = make_uint4(0u, 0u, 0u, 0u);
            if (gr < M) v = Ag[(size_t)gr * 16 + cc];
            *(uint4*)&As[row * 136 + cc * 8] = v;
        }
#pragma unroll
        for (int i = 0; i < 8; ++i) {
            int id = t + 256 * i, row = id >> 4, cc = id & 15;
            *(uint4*)&Bs[row * 136 + cc * 8] = Wg[(size_t)(colBase + row) * 16 + cc];
        }
        __syncthreads();
        const u16* aB = &As[(w * 16 + r) * 136 + half * 8];
        const u16* bB = &Bs[r * 136 + half * 8];
#pragma unroll
        for (int kk = 0; kk < 4; ++kk) {
            short8 af = *(const short8*)(aB + kk * 32);
#pragma unroll
            for (int ct = 0; ct < 8; ++ct) {
                short8 bf = *(const short8*)(bB + ct * (16 * 136) + kk * 32);
                acc[ct] = __builtin_amdgcn_mfma_f32_16x16x32_bf16(af, bf, acc[ct], 0, 0, 0);
            }
        }
    }

#pragma unroll
    for (int ct = 0; ct < 8; ++ct) {
        int col = colBase + ct * 16 + r;
        float bv = bias0[col];
        if (bias1) bv += bias1[col];
#pragma unroll
        for (int reg = 0; reg < 4; ++reg) {
            int row = rowBase + w * 16 + half * 4 + reg;
            if (row < M) {
                float v = acc[ct][reg] + bv;
                if (RELU) v = fmaxf(v, 0.f);
                C[(size_t)row * NC + col] = f2bf(v);
            }
        }
    }
}

// ---------------- output: out[N,3] = h4(bf16) @ W2.T(fp32) + b2, one wave/row ----------------
__global__ __launch_bounds__(256) void out_kernel(const u16* __restrict__ h4,
                                                  const float* __restrict__ W2,
                                                  const float* __restrict__ b2,
                                                  float* __restrict__ out, int n) {
    int w = (blockIdx.x * 256 + threadIdx.x) >> 6;
    int lane = threadIdx.x & 63;
    if (w >= n) return;
    uint2 hv = ((const uint2*)h4)[(size_t)w * 64 + lane];
    float h0 = bf_lo(hv.x), h1 = bf_hi(hv.x), h2 = bf_lo(hv.y), h3 = bf_hi(hv.y);
    float4 w0 = ((const float4*)W2)[0 * 64 + lane];
    float4 w1 = ((const float4*)W2)[1 * 64 + lane];
    float4 w2 = ((const float4*)W2)[2 * 64 + lane];
    float p0 = h0 * w0.x + h1 * w0.y + h2 * w0.z + h3 * w0.w;
    float p1 = h0 * w1.x + h1 * w1.y + h2 * w1.z + h3 * w1.w;
    float p2 = h0 * w2.x + h1 * w2.y + h2 * w2.z + h3 * w2.w;
#pragma unroll
    for (int off = 32; off > 0; off >>= 1) {
        p0 += __shfl_xor(p0, off);
        p1 += __shfl_xor(p1, off);
        p2 += __shfl_xor(p2, off);
    }
    if (lane == 0) {
        out[(size_t)w * 3 + 0] = p0 + b2[0];
        out[(size_t)w * 3 + 1] = p1 + b2[1];
        out[(size_t)w * 3 + 2] = p2 + b2[2];
    }
}

extern "C" void kernel_launch(void* const* d_in, const int* in_sizes, int n_in,
                              void* d_out, int out_size, void* d_ws, size_t ws_size,
                              hipStream_t stream) {
    const float* x   = (const float*)d_in[0];
    const int*   ei0 = (const int*)d_in[1];
    const int*   ei1 = (const int*)d_in[2];
    const float* Wl1 = (const float*)d_in[3];
    const float* bl1 = (const float*)d_in[4];
    const float* Wr1 = (const float*)d_in[5];
    const float* Wl2 = (const float*)d_in[6];
    const float* bl2 = (const float*)d_in[7];
    const float* Wr2 = (const float*)d_in[8];
    const float* Wsk = (const float*)d_in[9];
    const float* bsk = (const float*)d_in[10];
    const float* W1  = (const float*)d_in[11];
    const float* b1  = (const float*)d_in[12];
    const float* W2  = (const float*)d_in[13];
    const float* b2  = (const float*)d_in[14];
    float* out = (float*)d_out;

    const int N  = in_sizes[0] / DD;   // 50000
    const int E0 = in_sizes[1] / 2;    // 800000
    const int E1 = in_sizes[2] / 2;
    const int H  = in_sizes[12];       // 256

    const int* src0 = ei0;      const int* dst0 = ei0 + E0;
    const int* src1 = ei1;      const int* dst1 = ei1 + E1;

    const int nb   = (N + 255) >> SB;                  // 196 buckets
    const int Emax = (E0 > E1) ? E0 : E1;
    const int P    = (Emax + CH - 1) / CH;             // 196 partitions (<= 256)

    // workspace carve (256B aligned)
    char* wp = (char*)d_ws;
    auto carve = [&](size_t bytes) { char* p = wp; wp += (bytes + 255) & ~(size_t)255; return p; };
    u16* xh   = (u16*)carve((size_t)N * DD * 2);
    u16* aggh = (u16*)carve((size_t)N * DD * 2);
    u16* h1h  = (u16*)carve((size_t)N * DD * 2);
    u16* h3h  = (u16*)carve((size_t)N * DD * 2);
    u16* h4h  = (u16*)carve((size_t)N * H * 2);
    u16* wl1h = (u16*)carve((size_t)DD * DD * 2);
    u16* wr1h = (u16*)carve((size_t)DD * DD * 2);
    u16* wl2h = (u16*)carve((size_t)DD * DD * 2);
    u16* wr2h = (u16*)carve((size_t)DD * DD * 2);
    u16* wsh  = (u16*)carve((size_t)DD * DD * 2);
    u16* w1h  = (u16*)carve((size_t)H * DD * 2);
    int* deg0 = (int*)carve((size_t)N * 4);
    int* rp0  = (int*)carve((size_t)(N + 1) * 4);
    int* deg1 = (int*)carve((size_t)N * 4);
    int* rp1  = (int*)carve((size_t)(N + 1) * 4);
    u16* csr0 = (u16*)carve((size_t)E0 * 2);
    u16* csr1 = (u16*)carve((size_t)E1 * 2);
    unsigned* binned0 = (unsigned*)carve((size_t)E0 * 4);
    unsigned* binned1 = (unsigned*)carve((size_t)E1 * 4);
    int* bsum0  = (int*)carve((size_t)nb * 4);
    int* bsum1  = (int*)carve((size_t)nb * 4);
    int* hist1_0 = (int*)carve((size_t)nb * P * 4);
    int* hist1_1 = (int*)carve((size_t)nb * P * 4);

    // fused cast: x + 6 weight matrices
    CastJobs jb;
    const float* srcs[7] = {x, Wl1, Wr1, Wl2, Wr2, Wsk, W1};
    u16* dsts[7]         = {xh, wl1h, wr1h, wl2h, wr2h, wsh, w1h};
    int  cnts[7] = {N * DD, DD * DD, DD * DD, DD * DD, DD * DD, DD * DD, H * DD};
    int q = 0;
    for (int i = 0; i < 7; ++i) {
        jb.src[i] = (const float4*)srcs[i];
        jb.dst[i] = (uint2*)dsts[i];
        jb.qstart[i] = q;
        q += cnts[i] / 4;
    }
    jb.qstart[7] = q;

    const int gN   = (N + 255) / 256;
    const int gE   = (Emax + 255) / 256;
    const int gAgg = (N * 16 + 255) / 256;
    const int mB   = (N + 63) / 64;    // 782

    cast_kernel<<<(q + 255) / 256, 256, 0, stream>>>(jb);
    init_kernel<<<gN, 256, 0, stream>>>(deg0, deg1, N);
    hist_kernel<<<gE, 256, 0, stream>>>(dst0, deg0, dst1, deg1, E0, E1);
    scan_k1<<<2 * nb, 256, 0, stream>>>(deg0, rp0, bsum0, deg1, rp1, bsum1, N, nb);
    scan_k2<<<2, 256, 0, stream>>>(bsum0, bsum1, nb);
    scan_k3<<<2 * nb, 256, 0, stream>>>(rp0, bsum0, E0, rp1, bsum1, E1, N, nb);
    hist1_kernel<<<dim3(P, 2), 256, 0, stream>>>(dst0, hist1_0, dst1, hist1_1, E0, E1, nb, P);
    offs_kernel<<<dim3(nb, 2), 256, 0, stream>>>(hist1_0, rp0, hist1_1, rp1, P);
    scatter1_kernel<<<dim3(P, 2), 256, 0, stream>>>(src0, dst0, hist1_0, binned0,
                                                    src1, dst1, hist1_1, binned1, E0, E1, nb, P);
    place_kernel<<<dim3(nb, 2), 256, 0, stream>>>(binned0, rp0, csr0, binned1, rp1, csr1, N, nb);

    // layer 1
    agg_mean_bf16<<<gAgg, 256, 0, stream>>>(xh, csr0, rp0, aggh, N);
    mfma_gemm<false><<<mB, 256, 0, stream>>>(
        aggh, wl1h, xh, wr1h, nullptr, nullptr, 2, bl1, nullptr, h1h, N, DD, mB);

    // layer 2 + skip
    agg_mean_bf16<<<gAgg, 256, 0, stream>>>(h1h, csr1, rp1, aggh, N);
    mfma_gemm<false><<<mB, 256, 0, stream>>>(
        aggh, wl2h, h1h, wr2h, xh, wsh, 3, bl2, bsk, h3h, N, DD, mB);

    // MLP hidden (NC=256 -> 2 column blocks)
    mfma_gemm<true><<<mB * (H / 128), 256, 0, stream>>>(
        h3h, w1h, nullptr, nullptr, nullptr, nullptr, 1, b1, nullptr, h4h, N, H, mB);

    // output layer
    const int gOut = (N * 64 + 255) / 256;
    out_kernel<<<gOut, 256, 0, stream>>>(h4h, W2, b2, out, N);
}

// Round 5
// 309.695 us; speedup vs baseline: 3.3720x; 1.1711x over previous
//
#include <hip/hip_runtime.h>
#include <hip/hip_bf16.h>

// GraphSAGE net on MI355X: bf16 MFMA GEMMs + bf16 gather aggregation.
// N=50000, E=800000/layer, D=128, H=256, O=3.
//
// CSR build = deterministic partitioned counting sort with ZERO global atomics
// (r3 lesson: same-address device atomics ~85ns; r4 lesson: even spread device
// atomics cost a ~32B fabric RMW each -> 50MB for 1.6M ops). All counts come
// from LDS histograms:
//   hist1[bucket][partition] (LDS)  -> bscan (bucket bases, rp[N])
//   -> offs (per-bucket partition scan) -> scatter1 (LDS bump, plain stores)
//   -> place (per-bucket: LDS node histogram + local scan -> writes rp AND csr)

#define DD 128
#define SB 8               // 256 nodes per bucket
#define CH 4096            // edges per partition chunk
typedef unsigned short u16;
typedef __attribute__((ext_vector_type(8))) short short8;
typedef __attribute__((ext_vector_type(4))) float f32x4;

__device__ inline u16 f2bf(float f) {
    __hip_bfloat16 h = __float2bfloat16(f);
    u16 u;
    __builtin_memcpy(&u, &h, 2);
    return u;
}
__device__ inline float bf_lo(unsigned u) { union { unsigned x; float f; } c; c.x = u << 16; return c.f; }
__device__ inline float bf_hi(unsigned u) { union { unsigned x; float f; } c; c.x = u & 0xffff0000u; return c.f; }

// ---------------- fused fp32 -> bf16 cast ----------------
struct CastJobs {
    const float4* src[7];
    uint2* dst[7];
    int qstart[8];
};
__global__ __launch_bounds__(256) void cast_kernel(CastJobs jb) {
    int q = blockIdx.x * 256 + threadIdx.x;
    if (q >= jb.qstart[7]) return;
    int i = 0;
#pragma unroll
    for (int k = 1; k < 7; ++k) if (q >= jb.qstart[k]) i = k;
    int local = q - jb.qstart[i];
    float4 v = jb.src[i][local];
    unsigned lo = (unsigned)f2bf(v.x) | ((unsigned)f2bf(v.y) << 16);
    unsigned hi = (unsigned)f2bf(v.z) | ((unsigned)f2bf(v.w) << 16);
    jb.dst[i][local] = make_uint2(lo, hi);
}

// ---------------- CSR build ----------------
// hist1: per-(bucket,partition) counts via LDS histogram. grid (P, 2).
__global__ __launch_bounds__(256) void hist1_kernel(const int* __restrict__ dst0, int* __restrict__ h0,
                                                    const int* __restrict__ dst1, int* __restrict__ h1,
                                                    int e0, int e1, int nb, int P) {
    int arr = blockIdx.y;
    const int* dst = arr ? dst1 : dst0;
    int* hist = arr ? h1 : h0;
    int e = arr ? e1 : e0;
    __shared__ int h[256];
    int t = threadIdx.x;
    h[t] = 0;
    __syncthreads();
    int base = blockIdx.x * CH;
    int hi = min(base + CH, e);
    for (int i = base + t; i < hi; i += 256) atomicAdd(&h[dst[i] >> SB], 1);
    __syncthreads();
    if (t < nb) hist[t * P + blockIdx.x] = h[t];   // [bucket][partition]
}

// bscan: bucket totals (sum over partitions) -> exclusive scan -> bbase; rp[n]=E. grid(2).
__global__ __launch_bounds__(256) void bscan_kernel(const int* __restrict__ h0, int* __restrict__ bb0, int* __restrict__ rp0, int e0,
                                                    const int* __restrict__ h1, int* __restrict__ bb1, int* __restrict__ rp1, int e1,
                                                    int nb, int P, int n) {
    int arr = blockIdx.x;
    const int* hist = arr ? h1 : h0;
    int* bb = arr ? bb1 : bb0;
    int* rp = arr ? rp1 : rp0;
    int E = arr ? e1 : e0;
    __shared__ int s[256];
    int t = threadIdx.x;
    int v = 0;
    if (t < nb) {
        const int* row = hist + (size_t)t * P;
        for (int p = 0; p < P; ++p) v += row[p];
    }
    s[t] = v;
    __syncthreads();
    for (int off = 1; off < 256; off <<= 1) {
        int u = (t >= off) ? s[t - off] : 0;
        __syncthreads();
        s[t] += u;
        __syncthreads();
    }
    if (t < nb) bb[t] = s[t] - v;
    if (t == 0) { bb[nb] = E; rp[n] = E; }
}

// offs: exclusive scan over partitions per bucket, + bbase[b]. In-place. grid (nb, 2).
__global__ __launch_bounds__(256) void offs_kernel(int* __restrict__ h0, const int* __restrict__ bb0,
                                                   int* __restrict__ h1, const int* __restrict__ bb1,
                                                   int P) {
    int arr = blockIdx.y;
    int* hist = arr ? h1 : h0;
    const int* bb = arr ? bb1 : bb0;
    int b = blockIdx.x;
    __shared__ int s[256];
    int t = threadIdx.x;
    int v = (t < P) ? hist[b * P + t] : 0;
    s[t] = v;
    __syncthreads();
    for (int off = 1; off < 256; off <<= 1) {
        int u = (t >= off) ? s[t - off] : 0;
        __syncthreads();
        s[t] += u;
        __syncthreads();
    }
    if (t < P) hist[b * P + t] = s[t] - v + bb[b];
}

// scatter1: chunk p writes its edges to bucket-contiguous binned via LDS bump counters.
// Plain stores only (no global atomics). grid (P, 2).
__global__ __launch_bounds__(256) void scatter1_kernel(
    const int* __restrict__ src0, const int* __restrict__ dst0, const int* __restrict__ h0, unsigned* __restrict__ binned0,
    const int* __restrict__ src1, const int* __restrict__ dst1, const int* __restrict__ h1, unsigned* __restrict__ binned1,
    int e0, int e1, int nb, int P) {
    int arr = blockIdx.y;
    const int* src = arr ? src1 : src0;
    const int* dst = arr ? dst1 : dst0;
    const int* hist = arr ? h1 : h0;
    unsigned* binned = arr ? binned1 : binned0;
    int e = arr ? e1 : e0;
    int p = blockIdx.x;
    __shared__ int cnt[256];
    int t = threadIdx.x;
    if (t < nb) cnt[t] = hist[t * P + p];
    __syncthreads();
    int base = p * CH;
    int hi = min(base + CH, e);
    for (int i = base + t; i < hi; i += 256) {
        int d = dst[i];
        int pos = atomicAdd(&cnt[d >> SB], 1);        // LDS atomic
        binned[pos] = ((unsigned)d << 16) | (unsigned)src[i];
    }
}

// place: one block per bucket. Builds the 256-node histogram from its own binned
// range, local exclusive scan -> writes rp[node] and dense u16 CSR. grid (nb, 2).
__global__ __launch_bounds__(256) void place_kernel(
    const unsigned* __restrict__ binned0, const int* __restrict__ bb0, int* __restrict__ rp0, u16* __restrict__ csr0,
    const unsigned* __restrict__ binned1, const int* __restrict__ bb1, int* __restrict__ rp1, u16* __restrict__ csr1,
    int n, int nb) {
    int arr = blockIdx.y;
    const unsigned* binned = arr ? binned1 : binned0;
    const int* bb = arr ? bb1 : bb0;
    int* rp = arr ? rp1 : rp0;
    u16* csr = arr ? csr1 : csr0;
    int b = blockIdx.x;
    __shared__ int cnt[256];
    __shared__ int s[256];
    int t = threadIdx.x;
    int base = bb[b], end = bb[b + 1];
    cnt[t] = 0;
    __syncthreads();
    for (int i = base + t; i < end; i += 256)
        atomicAdd(&cnt[(binned[i] >> 16) & 255], 1);   // LDS atomic
    __syncthreads();
    int deg = cnt[t];
    s[t] = deg;
    __syncthreads();
    for (int off = 1; off < 256; off <<= 1) {
        int u = (t >= off) ? s[t - off] : 0;
        __syncthreads();
        s[t] += u;
        __syncthreads();
    }
    int gpos = base + s[t] - deg;                      // global CSR start for this node
    int node = (b << SB) + t;
    if (node < n) rp[node] = gpos;
    cnt[t] = gpos;                                     // re-seed as bump counter
    __syncthreads();
    for (int i = base + t; i < end; i += 256) {
        unsigned pk = binned[i];
        int ld = (pk >> 16) & 255;
        int pos = atomicAdd(&cnt[ld], 1);              // LDS atomic
        csr[pos] = (u16)(pk & 0xffffu);
    }
}

// ---------------- mean aggregation: bf16 gather, fp32 accum ----------------
__global__ __launch_bounds__(256) void agg_mean_bf16(const u16* __restrict__ X,
                                                     const u16* __restrict__ csr,
                                                     const int* __restrict__ rp,
                                                     u16* __restrict__ out, int n) {
    int g = (blockIdx.x * 256 + threadIdx.x) >> 4;
    int lane = threadIdx.x & 15;
    if (g >= n) return;
    int start = rp[g];
    int end = rp[g + 1];
    int d = end - start;
    const uint4* X4 = (const uint4*)X;
    float acc[8] = {0.f, 0.f, 0.f, 0.f, 0.f, 0.f, 0.f, 0.f};
    int e = start;
    for (; e + 1 < end; e += 2) {
        int s0 = csr[e], s1 = csr[e + 1];
        uint4 v0 = X4[(size_t)s0 * 16 + lane];
        uint4 v1 = X4[(size_t)s1 * 16 + lane];
        acc[0] += bf_lo(v0.x) + bf_lo(v1.x); acc[1] += bf_hi(v0.x) + bf_hi(v1.x);
        acc[2] += bf_lo(v0.y) + bf_lo(v1.y); acc[3] += bf_hi(v0.y) + bf_hi(v1.y);
        acc[4] += bf_lo(v0.z) + bf_lo(v1.z); acc[5] += bf_hi(v0.z) + bf_hi(v1.z);
        acc[6] += bf_lo(v0.w) + bf_lo(v1.w); acc[7] += bf_hi(v0.w) + bf_hi(v1.w);
    }
    if (e < end) {
        int s0 = csr[e];
        uint4 v0 = X4[(size_t)s0 * 16 + lane];
        acc[0] += bf_lo(v0.x); acc[1] += bf_hi(v0.x);
        acc[2] += bf_lo(v0.y); acc[3] += bf_hi(v0.y);
        acc[4] += bf_lo(v0.z); acc[5] += bf_hi(v0.z);
        acc[6] += bf_lo(v0.w); acc[7] += bf_hi(v0.w);
    }
    float scale = 1.0f / (float)max(d, 1);
    uint4 r;
    r.x = (unsigned)f2bf(acc[0] * scale) | ((unsigned)f2bf(acc[1] * scale) << 16);
    r.y = (unsigned)f2bf(acc[2] * scale) | ((unsigned)f2bf(acc[3] * scale) << 16);
    r.z = (unsigned)f2bf(acc[4] * scale) | ((unsigned)f2bf(acc[5] * scale) << 16);
    r.w = (unsigned)f2bf(acc[6] * scale) | ((unsigned)f2bf(acc[7] * scale) << 16);
    ((uint4*)out)[(size_t)g * 16 + lane] = r;
}

// ---------------- MFMA GEMM: C = sum_p A_p @ W_p.T + bias [relu], bf16 in/out ----------------
template <bool RELU>
__global__ __launch_bounds__(256) void mfma_gemm(
    const u16* __restrict__ A0, const u16* __restrict__ W0,
    const u16* __restrict__ A1, const u16* __restrict__ W1,
    const u16* __restrict__ A2, const u16* __restrict__ W2,
    int npair,
    const float* __restrict__ bias0, const float* __restrict__ bias1,
    u16* __restrict__ C, int M, int NC, int mB) {
    __shared__ u16 As[64 * 136];
    __shared__ u16 Bs[128 * 136];
    const int t = threadIdx.x;
    const int rowBase = (blockIdx.x % mB) * 64;
    const int colBase = (blockIdx.x / mB) * 128;
    const int w = t >> 6, lane = t & 63, r = lane & 15, half = lane >> 4;

    const u16* Ap[3] = {A0, A1, A2};
    const u16* Wp[3] = {W0, W1, W2};

    f32x4 acc[8];
#pragma unroll
    for (int i = 0; i < 8; ++i) acc[i] = (f32x4){0.f, 0.f, 0.f, 0.f};

    for (int p = 0; p < npair; ++p) {
        if (p) __syncthreads();
        const uint4* Ag = (const uint4*)Ap[p];
        const uint4* Wg = (const uint4*)Wp[p];
#pragma unroll
        for (int i = 0; i < 4; ++i) {
            int id = t + 256 * i, row = id >> 4, cc = id & 15;
            int gr = rowBase + row;
            uint4 v = make_uint4(0u, 0u, 0u, 0u);
            if (gr < M) v = Ag[(size_t)gr * 16 + cc];
            *(uint4*)&As[row * 136 + cc * 8] = v;
        }
#pragma unroll
        for (int i = 0; i < 8; ++i) {
            int id = t + 256 * i, row = id >> 4, cc = id & 15;
            *(uint4*)&Bs[row * 136 + cc * 8] = Wg[(size_t)(colBase + row) * 16 + cc];
        }
        __syncthreads();
        const u16* aB = &As[(w * 16 + r) * 136 + half * 8];
        const u16* bB = &Bs[r * 136 + half * 8];
#pragma unroll
        for (int kk = 0; kk < 4; ++kk) {
            short8 af = *(const short8*)(aB + kk * 32);
#pragma unroll
            for (int ct = 0; ct < 8; ++ct) {
                short8 bf = *(const short8*)(bB + ct * (16 * 136) + kk * 32);
                acc[ct] = __builtin_amdgcn_mfma_f32_16x16x32_bf16(af, bf, acc[ct], 0, 0, 0);
            }
        }
    }

#pragma unroll
    for (int ct = 0; ct < 8; ++ct) {
        int col = colBase + ct * 16 + r;
        float bv = bias0[col];
        if (bias1) bv += bias1[col];
#pragma unroll
        for (int reg = 0; reg < 4; ++reg) {
            int row = rowBase + w * 16 + half * 4 + reg;
            if (row < M) {
                float v = acc[ct][reg] + bv;
                if (RELU) v = fmaxf(v, 0.f);
                C[(size_t)row * NC + col] = f2bf(v);
            }
        }
    }
}

// ---------------- output: out[N,3] = h4(bf16) @ W2.T(fp32) + b2, one wave/row ----------------
__global__ __launch_bounds__(256) void out_kernel(const u16* __restrict__ h4,
                                                  const float* __restrict__ W2,
                                                  const float* __restrict__ b2,
                                                  float* __restrict__ out, int n) {
    int w = (blockIdx.x * 256 + threadIdx.x) >> 6;
    int lane = threadIdx.x & 63;
    if (w >= n) return;
    uint2 hv = ((const uint2*)h4)[(size_t)w * 64 + lane];
    float h0 = bf_lo(hv.x), h1 = bf_hi(hv.x), h2 = bf_lo(hv.y), h3 = bf_hi(hv.y);
    float4 w0 = ((const float4*)W2)[0 * 64 + lane];
    float4 w1 = ((const float4*)W2)[1 * 64 + lane];
    float4 w2 = ((const float4*)W2)[2 * 64 + lane];
    float p0 = h0 * w0.x + h1 * w0.y + h2 * w0.z + h3 * w0.w;
    float p1 = h0 * w1.x + h1 * w1.y + h2 * w1.z + h3 * w1.w;
    float p2 = h0 * w2.x + h1 * w2.y + h2 * w2.z + h3 * w2.w;
#pragma unroll
    for (int off = 32; off > 0; off >>= 1) {
        p0 += __shfl_xor(p0, off);
        p1 += __shfl_xor(p1, off);
        p2 += __shfl_xor(p2, off);
    }
    if (lane == 0) {
        out[(size_t)w * 3 + 0] = p0 + b2[0];
        out[(size_t)w * 3 + 1] = p1 + b2[1];
        out[(size_t)w * 3 + 2] = p2 + b2[2];
    }
}

extern "C" void kernel_launch(void* const* d_in, const int* in_sizes, int n_in,
                              void* d_out, int out_size, void* d_ws, size_t ws_size,
                              hipStream_t stream) {
    const float* x   = (const float*)d_in[0];
    const int*   ei0 = (const int*)d_in[1];
    const int*   ei1 = (const int*)d_in[2];
    const float* Wl1 = (const float*)d_in[3];
    const float* bl1 = (const float*)d_in[4];
    const float* Wr1 = (const float*)d_in[5];
    const float* Wl2 = (const float*)d_in[6];
    const float* bl2 = (const float*)d_in[7];
    const float* Wr2 = (const float*)d_in[8];
    const float* Wsk = (const float*)d_in[9];
    const float* bsk = (const float*)d_in[10];
    const float* W1  = (const float*)d_in[11];
    const float* b1  = (const float*)d_in[12];
    const float* W2  = (const float*)d_in[13];
    const float* b2  = (const float*)d_in[14];
    float* out = (float*)d_out;

    const int N  = in_sizes[0] / DD;   // 50000
    const int E0 = in_sizes[1] / 2;    // 800000
    const int E1 = in_sizes[2] / 2;
    const int H  = in_sizes[12];       // 256

    const int* src0 = ei0;      const int* dst0 = ei0 + E0;
    const int* src1 = ei1;      const int* dst1 = ei1 + E1;

    const int nb   = (N + 255) >> SB;                  // 196 buckets
    const int Emax = (E0 > E1) ? E0 : E1;
    const int P    = (Emax + CH - 1) / CH;             // 196 partitions (<= 256)

    // workspace carve (256B aligned)
    char* wp = (char*)d_ws;
    auto carve = [&](size_t bytes) { char* p = wp; wp += (bytes + 255) & ~(size_t)255; return p; };
    u16* xh   = (u16*)carve((size_t)N * DD * 2);
    u16* aggh = (u16*)carve((size_t)N * DD * 2);
    u16* h1h  = (u16*)carve((size_t)N * DD * 2);
    u16* h3h  = (u16*)carve((size_t)N * DD * 2);
    u16* h4h  = (u16*)carve((size_t)N * H * 2);
    u16* wl1h = (u16*)carve((size_t)DD * DD * 2);
    u16* wr1h = (u16*)carve((size_t)DD * DD * 2);
    u16* wl2h = (u16*)carve((size_t)DD * DD * 2);
    u16* wr2h = (u16*)carve((size_t)DD * DD * 2);
    u16* wsh  = (u16*)carve((size_t)DD * DD * 2);
    u16* w1h  = (u16*)carve((size_t)H * DD * 2);
    int* rp0  = (int*)carve((size_t)(N + 1) * 4);
    int* rp1  = (int*)carve((size_t)(N + 1) * 4);
    u16* csr0 = (u16*)carve((size_t)E0 * 2);
    u16* csr1 = (u16*)carve((size_t)E1 * 2);
    unsigned* binned0 = (unsigned*)carve((size_t)E0 * 4);
    unsigned* binned1 = (unsigned*)carve((size_t)E1 * 4);
    int* hist1_0 = (int*)carve((size_t)nb * P * 4);
    int* hist1_1 = (int*)carve((size_t)nb * P * 4);
    int* bb0 = (int*)carve((size_t)(nb + 1) * 4);
    int* bb1 = (int*)carve((size_t)(nb + 1) * 4);

    // fused cast: x + 6 weight matrices
    CastJobs jb;
    const float* srcs[7] = {x, Wl1, Wr1, Wl2, Wr2, Wsk, W1};
    u16* dsts[7]         = {xh, wl1h, wr1h, wl2h, wr2h, wsh, w1h};
    int  cnts[7] = {N * DD, DD * DD, DD * DD, DD * DD, DD * DD, DD * DD, H * DD};
    int q = 0;
    for (int i = 0; i < 7; ++i) {
        jb.src[i] = (const float4*)srcs[i];
        jb.dst[i] = (uint2*)dsts[i];
        jb.qstart[i] = q;
        q += cnts[i] / 4;
    }
    jb.qstart[7] = q;

    const int gAgg = (N * 16 + 255) / 256;
    const int mB   = (N + 63) / 64;    // 782

    cast_kernel<<<(q + 255) / 256, 256, 0, stream>>>(jb);
    hist1_kernel<<<dim3(P, 2), 256, 0, stream>>>(dst0, hist1_0, dst1, hist1_1, E0, E1, nb, P);
    bscan_kernel<<<2, 256, 0, stream>>>(hist1_0, bb0, rp0, E0, hist1_1, bb1, rp1, E1, nb, P, N);
    offs_kernel<<<dim3(nb, 2), 256, 0, stream>>>(hist1_0, bb0, hist1_1, bb1, P);
    scatter1_kernel<<<dim3(P, 2), 256, 0, stream>>>(src0, dst0, hist1_0, binned0,
                                                    src1, dst1, hist1_1, binned1, E0, E1, nb, P);
    place_kernel<<<dim3(nb, 2), 256, 0, stream>>>(binned0, bb0, rp0, csr0,
                                                  binned1, bb1, rp1, csr1, N, nb);

    // layer 1
    agg_mean_bf16<<<gAgg, 256, 0, stream>>>(xh, csr0, rp0, aggh, N);
    mfma_gemm<false><<<mB, 256, 0, stream>>>(
        aggh, wl1h, xh, wr1h, nullptr, nullptr, 2, bl1, nullptr, h1h, N, DD, mB);

    // layer 2 + skip
    agg_mean_bf16<<<gAgg, 256, 0, stream>>>(h1h, csr1, rp1, aggh, N);
    mfma_gemm<false><<<mB, 256, 0, stream>>>(
        aggh, wl2h, h1h, wr2h, xh, wsh, 3, bl2, bsk, h3h, N, DD, mB);

    // MLP hidden (NC=256 -> 2 column blocks)
    mfma_gemm<true><<<mB * (H / 128), 256, 0, stream>>>(
        h3h, w1h, nullptr, nullptr, nullptr, nullptr, 1, b1, nullptr, h4h, N, H, mB);

    // output layer
    const int gOut = (N * 64 + 255) / 256;
    out_kernel<<<gOut, 256, 0, stream>>>(h4h, W2, b2, out, N);
}

// Round 6
// 294.195 us; speedup vs baseline: 3.5496x; 1.0527x over previous
//
#include <hip/hip_runtime.h>
#include <hip/hip_bf16.h>

// GraphSAGE net on MI355X — linearity-restructured:
//   lin_l(mean_j x_j) = mean_j lin_l(x_j)  =>  transform-then-aggregate.
//   G1 = x @ [Wl1;Wr1;Ws].T   (fp32 A, cast in staging; NC=384)
//   h1 = mean_nbr0(G1L) + G1M + bl1
//   G2 = h1 @ [Wl2;Wr2].T     (NC=256)
//   h3 = mean_nbr1(G2L) + G2R + G1R + bl2 + bs
//   out = relu(h3@W1.T+b1) @ W2.T + b2   (fused: h4 never leaves registers)
// CSR build = zero-global-atomic partitioned counting sort (r3/r4 lessons:
// same-address device atomics ~85ns; spread device atomics ~32B fabric RMW each).

#define DD 128
#define SB 8               // 256 nodes per bucket
#define CH 4096            // edges per partition chunk
typedef unsigned short u16;
typedef __attribute__((ext_vector_type(8))) short short8;
typedef __attribute__((ext_vector_type(4))) float f32x4;

__device__ inline u16 f2bf(float f) {
    __hip_bfloat16 h = __float2bfloat16(f);
    u16 u;
    __builtin_memcpy(&u, &h, 2);
    return u;
}
__device__ inline unsigned pack2(float lo, float hi) {
    return (unsigned)f2bf(lo) | ((unsigned)f2bf(hi) << 16);
}
__device__ inline float bf_lo(unsigned u) { union { unsigned x; float f; } c; c.x = u << 16; return c.f; }
__device__ inline float bf_hi(unsigned u) { union { unsigned x; float f; } c; c.x = u & 0xffff0000u; return c.f; }

// ---------------- weight cast fp32 -> bf16 (concat slots) ----------------
struct CastJobs {
    const float4* src[6];
    uint2* dst[6];
    int qstart[7];
};
__global__ __launch_bounds__(256) void cast_kernel(CastJobs jb) {
    int q = blockIdx.x * 256 + threadIdx.x;
    if (q >= jb.qstart[6]) return;
    int i = 0;
#pragma unroll
    for (int k = 1; k < 6; ++k) if (q >= jb.qstart[k]) i = k;
    int local = q - jb.qstart[i];
    float4 v = jb.src[i][local];
    jb.dst[i][local] = make_uint2(pack2(v.x, v.y), pack2(v.z, v.w));
}

// ---------------- CSR build ----------------
// hist1: per-(bucket,partition) counts via LDS histogram. grid (P, 2).
__global__ __launch_bounds__(256) void hist1_kernel(const int* __restrict__ dst0, int* __restrict__ h0,
                                                    const int* __restrict__ dst1, int* __restrict__ h1,
                                                    int e0, int e1, int nb, int P) {
    int arr = blockIdx.y;
    const int* dst = arr ? dst1 : dst0;
    int* hist = arr ? h1 : h0;
    int e = arr ? e1 : e0;
    __shared__ int h[256];
    int t = threadIdx.x;
    h[t] = 0;
    __syncthreads();
    int base = blockIdx.x * CH;
    int hi = min(base + CH, e);
    for (int i = base + t; i < hi; i += 256) atomicAdd(&h[dst[i] >> SB], 1);
    __syncthreads();
    if (t < nb) hist[t * P + blockIdx.x] = h[t];   // [bucket][partition]
}

// bscan: bucket totals -> exclusive scan -> bbase; rp[n]=E. grid(2).
__global__ __launch_bounds__(256) void bscan_kernel(const int* __restrict__ h0, int* __restrict__ bb0, int* __restrict__ rp0, int e0,
                                                    const int* __restrict__ h1, int* __restrict__ bb1, int* __restrict__ rp1, int e1,
                                                    int nb, int P, int n) {
    int arr = blockIdx.x;
    const int* hist = arr ? h1 : h0;
    int* bb = arr ? bb1 : bb0;
    int* rp = arr ? rp1 : rp0;
    int E = arr ? e1 : e0;
    __shared__ int s[256];
    int t = threadIdx.x;
    int v = 0;
    if (t < nb) {
        const int* row = hist + (size_t)t * P;
        for (int p = 0; p < P; ++p) v += row[p];
    }
    s[t] = v;
    __syncthreads();
    for (int off = 1; off < 256; off <<= 1) {
        int u = (t >= off) ? s[t - off] : 0;
        __syncthreads();
        s[t] += u;
        __syncthreads();
    }
    if (t < nb) bb[t] = s[t] - v;
    if (t == 0) { bb[nb] = E; rp[n] = E; }
}

// offs: exclusive scan over partitions per bucket, + bbase[b]. In-place. grid (nb, 2).
__global__ __launch_bounds__(256) void offs_kernel(int* __restrict__ h0, const int* __restrict__ bb0,
                                                   int* __restrict__ h1, const int* __restrict__ bb1,
                                                   int P) {
    int arr = blockIdx.y;
    int* hist = arr ? h1 : h0;
    const int* bb = arr ? bb1 : bb0;
    int b = blockIdx.x;
    __shared__ int s[256];
    int t = threadIdx.x;
    int v = (t < P) ? hist[b * P + t] : 0;
    s[t] = v;
    __syncthreads();
    for (int off = 1; off < 256; off <<= 1) {
        int u = (t >= off) ? s[t - off] : 0;
        __syncthreads();
        s[t] += u;
        __syncthreads();
    }
    if (t < P) hist[b * P + t] = s[t] - v + bb[b];
}

// scatter1: chunk p -> bucket-contiguous binned via LDS bump counters, plain stores. grid (P, 2).
__global__ __launch_bounds__(256) void scatter1_kernel(
    const int* __restrict__ src0, const int* __restrict__ dst0, const int* __restrict__ h0, unsigned* __restrict__ binned0,
    const int* __restrict__ src1, const int* __restrict__ dst1, const int* __restrict__ h1, unsigned* __restrict__ binned1,
    int e0, int e1, int nb, int P) {
    int arr = blockIdx.y;
    const int* src = arr ? src1 : src0;
    const int* dst = arr ? dst1 : dst0;
    const int* hist = arr ? h1 : h0;
    unsigned* binned = arr ? binned1 : binned0;
    int e = arr ? e1 : e0;
    int p = blockIdx.x;
    __shared__ int cnt[256];
    int t = threadIdx.x;
    if (t < nb) cnt[t] = hist[t * P + p];
    __syncthreads();
    int base = p * CH;
    int hi = min(base + CH, e);
    for (int i = base + t; i < hi; i += 256) {
        int d = dst[i];
        int pos = atomicAdd(&cnt[d >> SB], 1);        // LDS atomic
        binned[pos] = ((unsigned)d << 16) | (unsigned)src[i];
    }
}

// place: per bucket: LDS node histogram + local scan -> rp[node] and dense u16 CSR. grid (nb, 2).
__global__ __launch_bounds__(256) void place_kernel(
    const unsigned* __restrict__ binned0, const int* __restrict__ bb0, int* __restrict__ rp0, u16* __restrict__ csr0,
    const unsigned* __restrict__ binned1, const int* __restrict__ bb1, int* __restrict__ rp1, u16* __restrict__ csr1,
    int n, int nb) {
    int arr = blockIdx.y;
    const unsigned* binned = arr ? binned1 : binned0;
    const int* bb = arr ? bb1 : bb0;
    int* rp = arr ? rp1 : rp0;
    u16* csr = arr ? csr1 : csr0;
    int b = blockIdx.x;
    __shared__ int cnt[256];
    __shared__ int s[256];
    int t = threadIdx.x;
    int base = bb[b], end = bb[b + 1];
    cnt[t] = 0;
    __syncthreads();
    for (int i = base + t; i < end; i += 256)
        atomicAdd(&cnt[(binned[i] >> 16) & 255], 1);   // LDS atomic
    __syncthreads();
    int deg = cnt[t];
    s[t] = deg;
    __syncthreads();
    for (int off = 1; off < 256; off <<= 1) {
        int u = (t >= off) ? s[t - off] : 0;
        __syncthreads();
        s[t] += u;
        __syncthreads();
    }
    int gpos = base + s[t] - deg;
    int node = (b << SB) + t;
    if (node < n) rp[node] = gpos;
    cnt[t] = gpos;
    __syncthreads();
    for (int i = base + t; i < end; i += 256) {
        unsigned pk = binned[i];
        int ld = (pk >> 16) & 255;
        int pos = atomicAdd(&cnt[ld], 1);              // LDS atomic
        csr[pos] = (u16)(pk & 0xffffu);
    }
}

// ---------------- agg layer 1: h1 = mean_nbr(G1[:, :128]) + G1[:,128:256] + bl1 ----------------
// 16 lanes per node; G1 row = 48 uint4 (384 bf16).
__global__ __launch_bounds__(256) void agg1_kernel(const u16* __restrict__ G1,
                                                   const u16* __restrict__ csr,
                                                   const int* __restrict__ rp,
                                                   const float* __restrict__ bl1,
                                                   u16* __restrict__ h1, int n) {
    int g = (blockIdx.x * 256 + threadIdx.x) >> 4;
    int lane = threadIdx.x & 15;
    if (g >= n) return;
    int start = rp[g], end = rp[g + 1];
    int d = end - start;
    const uint4* X4 = (const uint4*)G1;
    float acc[8] = {0.f, 0.f, 0.f, 0.f, 0.f, 0.f, 0.f, 0.f};
    int e = start;
    for (; e + 1 < end; e += 2) {
        int s0 = csr[e], s1 = csr[e + 1];
        uint4 v0 = X4[(size_t)s0 * 48 + lane];
        uint4 v1 = X4[(size_t)s1 * 48 + lane];
        acc[0] += bf_lo(v0.x) + bf_lo(v1.x); acc[1] += bf_hi(v0.x) + bf_hi(v1.x);
        acc[2] += bf_lo(v0.y) + bf_lo(v1.y); acc[3] += bf_hi(v0.y) + bf_hi(v1.y);
        acc[4] += bf_lo(v0.z) + bf_lo(v1.z); acc[5] += bf_hi(v0.z) + bf_hi(v1.z);
        acc[6] += bf_lo(v0.w) + bf_lo(v1.w); acc[7] += bf_hi(v0.w) + bf_hi(v1.w);
    }
    if (e < end) {
        int s0 = csr[e];
        uint4 v0 = X4[(size_t)s0 * 48 + lane];
        acc[0] += bf_lo(v0.x); acc[1] += bf_hi(v0.x);
        acc[2] += bf_lo(v0.y); acc[3] += bf_hi(v0.y);
        acc[4] += bf_lo(v0.z); acc[5] += bf_hi(v0.z);
        acc[6] += bf_lo(v0.w); acc[7] += bf_hi(v0.w);
    }
    float sc = 1.0f / (float)max(d, 1);
    uint4 m = X4[(size_t)g * 48 + 16 + lane];          // G1M (x@Wr1.T)
    const float4* bl = (const float4*)bl1;
    float4 ba = bl[lane * 2], bb = bl[lane * 2 + 1];
    uint4 r;
    r.x = pack2(acc[0] * sc + bf_lo(m.x) + ba.x, acc[1] * sc + bf_hi(m.x) + ba.y);
    r.y = pack2(acc[2] * sc + bf_lo(m.y) + ba.z, acc[3] * sc + bf_hi(m.y) + ba.w);
    r.z = pack2(acc[4] * sc + bf_lo(m.z) + bb.x, acc[5] * sc + bf_hi(m.z) + bb.y);
    r.w = pack2(acc[6] * sc + bf_lo(m.w) + bb.z, acc[7] * sc + bf_hi(m.w) + bb.w);
    ((uint4*)h1)[(size_t)g * 16 + lane] = r;
}

// ---------------- agg layer 2: h3 = mean_nbr(G2L) + G2R + G1R + bl2 + bs ----------------
// G2 row = 32 uint4; G1 row = 48 uint4 (right third at +32).
__global__ __launch_bounds__(256) void agg2_kernel(const u16* __restrict__ G2,
                                                   const u16* __restrict__ G1,
                                                   const u16* __restrict__ csr,
                                                   const int* __restrict__ rp,
                                                   const float* __restrict__ bl2,
                                                   const float* __restrict__ bs,
                                                   u16* __restrict__ h3, int n) {
    int g = (blockIdx.x * 256 + threadIdx.x) >> 4;
    int lane = threadIdx.x & 15;
    if (g >= n) return;
    int start = rp[g], end = rp[g + 1];
    int d = end - start;
    const uint4* X4 = (const uint4*)G2;
    float acc[8] = {0.f, 0.f, 0.f, 0.f, 0.f, 0.f, 0.f, 0.f};
    int e = start;
    for (; e + 1 < end; e += 2) {
        int s0 = csr[e], s1 = csr[e + 1];
        uint4 v0 = X4[(size_t)s0 * 32 + lane];
        uint4 v1 = X4[(size_t)s1 * 32 + lane];
        acc[0] += bf_lo(v0.x) + bf_lo(v1.x); acc[1] += bf_hi(v0.x) + bf_hi(v1.x);
        acc[2] += bf_lo(v0.y) + bf_lo(v1.y); acc[3] += bf_hi(v0.y) + bf_hi(v1.y);
        acc[4] += bf_lo(v0.z) + bf_lo(v1.z); acc[5] += bf_hi(v0.z) + bf_hi(v1.z);
        acc[6] += bf_lo(v0.w) + bf_lo(v1.w); acc[7] += bf_hi(v0.w) + bf_hi(v1.w);
    }
    if (e < end) {
        int s0 = csr[e];
        uint4 v0 = X4[(size_t)s0 * 32 + lane];
        acc[0] += bf_lo(v0.x); acc[1] += bf_hi(v0.x);
        acc[2] += bf_lo(v0.y); acc[3] += bf_hi(v0.y);
        acc[4] += bf_lo(v0.z); acc[5] += bf_hi(v0.z);
        acc[6] += bf_lo(v0.w); acc[7] += bf_hi(v0.w);
    }
    float sc = 1.0f / (float)max(d, 1);
    uint4 m2 = X4[(size_t)g * 32 + 16 + lane];                    // G2R (h1@Wr2.T)
    uint4 m1 = ((const uint4*)G1)[(size_t)g * 48 + 32 + lane];    // G1R (x@Ws.T)
    const float4* c2 = (const float4*)bl2;
    const float4* cs = (const float4*)bs;
    float4 ba = c2[lane * 2], bb = c2[lane * 2 + 1];
    float4 sa = cs[lane * 2], sb = cs[lane * 2 + 1];
    uint4 r;
    r.x = pack2(acc[0] * sc + bf_lo(m2.x) + bf_lo(m1.x) + ba.x + sa.x,
                acc[1] * sc + bf_hi(m2.x) + bf_hi(m1.x) + ba.y + sa.y);
    r.y = pack2(acc[2] * sc + bf_lo(m2.y) + bf_lo(m1.y) + ba.z + sa.z,
                acc[3] * sc + bf_hi(m2.y) + bf_hi(m1.y) + ba.w + sa.w);
    r.z = pack2(acc[4] * sc + bf_lo(m2.z) + bf_lo(m1.z) + bb.x + sb.x,
                acc[5] * sc + bf_hi(m2.z) + bf_hi(m1.z) + bb.y + sb.y);
    r.w = pack2(acc[6] * sc + bf_lo(m2.w) + bf_lo(m1.w) + bb.z + sb.z,
                acc[7] * sc + bf_hi(m2.w) + bf_hi(m1.w) + bb.w + sb.w);
    ((uint4*)h3)[(size_t)g * 16 + lane] = r;
}

// ---------------- MFMA GEMM: C = A @ W.T (+bias), bf16 out. A fp32 or bf16. ----------------
// BM=64, BN=128, whole K=128 staged. 256 thr = 4 waves, 16x16x32 MFMA.
template <bool F32A>
__global__ __launch_bounds__(256) void mfma_gemm(const void* __restrict__ Av,
                                                 const u16* __restrict__ W,
                                                 const float* __restrict__ bias,
                                                 u16* __restrict__ C, int M, int NC, int mB) {
    __shared__ u16 As[64 * 136];
    __shared__ u16 Bs[128 * 136];
    const int t = threadIdx.x;
    const int rowBase = (blockIdx.x % mB) * 64;
    const int colBase = (blockIdx.x / mB) * 128;
    const int w = t >> 6, lane = t & 63, r = lane & 15, half = lane >> 4;

    f32x4 acc[8];
#pragma unroll
    for (int i = 0; i < 8; ++i) acc[i] = (f32x4){0.f, 0.f, 0.f, 0.f};

#pragma unroll
    for (int i = 0; i < 4; ++i) {            // A: 64 rows x 16 chunks of 8 elems
        int id = t + 256 * i, row = id >> 4, cc = id & 15;
        int gr = rowBase + row;
        uint4 v = make_uint4(0u, 0u, 0u, 0u);
        if (gr < M) {
            if (F32A) {
                const float* A = (const float*)Av;
                float4 a = *(const float4*)&A[(size_t)gr * DD + cc * 8];
                float4 b = *(const float4*)&A[(size_t)gr * DD + cc * 8 + 4];
                v = make_uint4(pack2(a.x, a.y), pack2(a.z, a.w), pack2(b.x, b.y), pack2(b.z, b.w));
            } else {
                v = ((const uint4*)Av)[(size_t)gr * 16 + cc];
            }
        }
        *(uint4*)&As[row * 136 + cc * 8] = v;
    }
#pragma unroll
    for (int i = 0; i < 8; ++i) {            // W: 128 rows x 16 chunks
        int id = t + 256 * i, row = id >> 4, cc = id & 15;
        *(uint4*)&Bs[row * 136 + cc * 8] = ((const uint4*)W)[(size_t)(colBase + row) * 16 + cc];
    }
    __syncthreads();
    const u16* aB = &As[(w * 16 + r) * 136 + half * 8];
    const u16* bB = &Bs[r * 136 + half * 8];
#pragma unroll
    for (int kk = 0; kk < 4; ++kk) {
        short8 af = *(const short8*)(aB + kk * 32);
#pragma unroll
        for (int ct = 0; ct < 8; ++ct) {
            short8 bf = *(const short8*)(bB + ct * (16 * 136) + kk * 32);
            acc[ct] = __builtin_amdgcn_mfma_f32_16x16x32_bf16(af, bf, acc[ct], 0, 0, 0);
        }
    }

#pragma unroll
    for (int ct = 0; ct < 8; ++ct) {
        int col = colBase + ct * 16 + r;
        float bv = bias ? bias[col] : 0.f;
#pragma unroll
        for (int reg = 0; reg < 4; ++reg) {
            int row = rowBase + w * 16 + half * 4 + reg;
            if (row < M) C[(size_t)row * NC + col] = f2bf(acc[ct][reg] + bv);
        }
    }
}

// ---------------- fused MLP head: out[64,3] = relu(h3_tile@W1.T + b1) @ W2.T + b2 ----------------
// BM=64, full NC=256 in two staged column halves; h4 stays in registers.
__global__ __launch_bounds__(256) void gemm_out_kernel(const u16* __restrict__ h3,
                                                       const u16* __restrict__ W1,
                                                       const float* __restrict__ b1,
                                                       const float* __restrict__ W2,
                                                       const float* __restrict__ b2,
                                                       float* __restrict__ out, int M) {
    __shared__ u16 As[64 * 136];
    __shared__ u16 Bs[128 * 136];
    __shared__ float w2s[3 * 256];
    __shared__ float b1s[256];
    const int t = threadIdx.x;
    const int rowBase = blockIdx.x * 64;
    const int w = t >> 6, lane = t & 63, r = lane & 15, half = lane >> 4;

    // stage W2 (fp32 3x256) and b1
    for (int i = t; i < 768; i += 256) w2s[i] = W2[i];
    b1s[t] = b1[t];
#pragma unroll
    for (int i = 0; i < 4; ++i) {
        int id = t + 256 * i, row = id >> 4, cc = id & 15;
        int gr = rowBase + row;
        uint4 v = make_uint4(0u, 0u, 0u, 0u);
        if (gr < M) v = ((const uint4*)h3)[(size_t)gr * 16 + cc];
        *(uint4*)&As[row * 136 + cc * 8] = v;
    }

    f32x4 acc[2][8];
#pragma unroll
    for (int ch = 0; ch < 2; ++ch)
#pragma unroll
        for (int i = 0; i < 8; ++i) acc[ch][i] = (f32x4){0.f, 0.f, 0.f, 0.f};

    for (int ch = 0; ch < 2; ++ch) {
        __syncthreads();
        if (ch) {
            // re-stage Bs with second column half (needs all reads of first done)
        }
#pragma unroll
        for (int i = 0; i < 8; ++i) {
            int id = t + 256 * i, row = id >> 4, cc = id & 15;
            *(uint4*)&Bs[row * 136 + cc * 8] = ((const uint4*)W1)[(size_t)(ch * 128 + row) * 16 + cc];
        }
        __syncthreads();
        const u16* aB = &As[(w * 16 + r) * 136 + half * 8];
        const u16* bB = &Bs[r * 136 + half * 8];
#pragma unroll
        for (int kk = 0; kk < 4; ++kk) {
            short8 af = *(const short8*)(aB + kk * 32);
#pragma unroll
            for (int ct = 0; ct < 8; ++ct) {
                short8 bf = *(const short8*)(bB + ct * (16 * 136) + kk * 32);
                acc[ch][ct] = __builtin_amdgcn_mfma_f32_16x16x32_bf16(af, bf, acc[ch][ct], 0, 0, 0);
            }
        }
    }

    // epilogue: h4 = relu(acc + b1); p = h4 @ W2.T partials, reduce over 16-lane col groups
    float p[4][3] = {{0.f}};
#pragma unroll
    for (int ch = 0; ch < 2; ++ch) {
#pragma unroll
        for (int ct = 0; ct < 8; ++ct) {
            int col = ch * 128 + ct * 16 + r;
            float bv = b1s[col];
            float w0 = w2s[0 * 256 + col], w1 = w2s[1 * 256 + col], w2v = w2s[2 * 256 + col];
#pragma unroll
            for (int reg = 0; reg < 4; ++reg) {
                float h4 = fmaxf(acc[ch][ct][reg] + bv, 0.f);
                p[reg][0] += h4 * w0;
                p[reg][1] += h4 * w1;
                p[reg][2] += h4 * w2v;
            }
        }
    }
#pragma unroll
    for (int m = 1; m < 16; m <<= 1)
#pragma unroll
        for (int reg = 0; reg < 4; ++reg)
#pragma unroll
            for (int o = 0; o < 3; ++o) p[reg][o] += __shfl_xor(p[reg][o], m);
    if (r == 0) {
#pragma unroll
        for (int reg = 0; reg < 4; ++reg) {
            int row = rowBase + w * 16 + half * 4 + reg;
            if (row < M) {
                out[(size_t)row * 3 + 0] = p[reg][0] + b2[0];
                out[(size_t)row * 3 + 1] = p[reg][1] + b2[1];
                out[(size_t)row * 3 + 2] = p[reg][2] + b2[2];
            }
        }
    }
}

extern "C" void kernel_launch(void* const* d_in, const int* in_sizes, int n_in,
                              void* d_out, int out_size, void* d_ws, size_t ws_size,
                              hipStream_t stream) {
    const float* x   = (const float*)d_in[0];
    const int*   ei0 = (const int*)d_in[1];
    const int*   ei1 = (const int*)d_in[2];
    const float* Wl1 = (const float*)d_in[3];
    const float* bl1 = (const float*)d_in[4];
    const float* Wr1 = (const float*)d_in[5];
    const float* Wl2 = (const float*)d_in[6];
    const float* bl2 = (const float*)d_in[7];
    const float* Wr2 = (const float*)d_in[8];
    const float* Wsk = (const float*)d_in[9];
    const float* bsk = (const float*)d_in[10];
    const float* W1  = (const float*)d_in[11];
    const float* b1  = (const float*)d_in[12];
    const float* W2  = (const float*)d_in[13];
    const float* b2  = (const float*)d_in[14];
    float* out = (float*)d_out;

    const int N  = in_sizes[0] / DD;   // 50000
    const int E0 = in_sizes[1] / 2;    // 800000
    const int E1 = in_sizes[2] / 2;
    const int H  = in_sizes[12];       // 256

    const int* src0 = ei0;      const int* dst0 = ei0 + E0;
    const int* src1 = ei1;      const int* dst1 = ei1 + E1;

    const int nb   = (N + 255) >> SB;                  // 196 buckets
    const int Emax = (E0 > E1) ? E0 : E1;
    const int P    = (Emax + CH - 1) / CH;             // 196 partitions (<= 256)

    // workspace carve (256B aligned), ~115 MB
    char* wp = (char*)d_ws;
    auto carve = [&](size_t bytes) { char* p = wp; wp += (bytes + 255) & ~(size_t)255; return p; };
    u16* G1   = (u16*)carve((size_t)N * 384 * 2);
    u16* G2   = (u16*)carve((size_t)N * 256 * 2);
    u16* h1h  = (u16*)carve((size_t)N * DD * 2);
    u16* h3h  = (u16*)carve((size_t)N * DD * 2);
    u16* wc1  = (u16*)carve((size_t)384 * DD * 2);   // [Wl1;Wr1;Ws]
    u16* wc2  = (u16*)carve((size_t)256 * DD * 2);   // [Wl2;Wr2]
    u16* w1h  = (u16*)carve((size_t)H * DD * 2);
    int* rp0  = (int*)carve((size_t)(N + 1) * 4);
    int* rp1  = (int*)carve((size_t)(N + 1) * 4);
    u16* csr0 = (u16*)carve((size_t)E0 * 2);
    u16* csr1 = (u16*)carve((size_t)E1 * 2);
    unsigned* binned0 = (unsigned*)carve((size_t)E0 * 4);
    unsigned* binned1 = (unsigned*)carve((size_t)E1 * 4);
    int* hist1_0 = (int*)carve((size_t)nb * P * 4);
    int* hist1_1 = (int*)carve((size_t)nb * P * 4);
    int* bb0 = (int*)carve((size_t)(nb + 1) * 4);
    int* bb1 = (int*)carve((size_t)(nb + 1) * 4);

    // weight cast into concat slots
    CastJobs jb;
    const float* srcs[6] = {Wl1, Wr1, Wsk, Wl2, Wr2, W1};
    u16* dsts[6] = {wc1, wc1 + 128 * DD, wc1 + 256 * DD, wc2, wc2 + 128 * DD, w1h};
    int  cnts[6] = {DD * DD, DD * DD, DD * DD, DD * DD, DD * DD, H * DD};
    int q = 0;
    for (int i = 0; i < 6; ++i) {
        jb.src[i] = (const float4*)srcs[i];
        jb.dst[i] = (uint2*)dsts[i];
        jb.qstart[i] = q;
        q += cnts[i] / 4;
    }
    jb.qstart[6] = q;

    const int gAgg = (N * 16 + 255) / 256;
    const int mB   = (N + 63) / 64;    // 782

    cast_kernel<<<(q + 255) / 256, 256, 0, stream>>>(jb);
    hist1_kernel<<<dim3(P, 2), 256, 0, stream>>>(dst0, hist1_0, dst1, hist1_1, E0, E1, nb, P);
    bscan_kernel<<<2, 256, 0, stream>>>(hist1_0, bb0, rp0, E0, hist1_1, bb1, rp1, E1, nb, P, N);
    offs_kernel<<<dim3(nb, 2), 256, 0, stream>>>(hist1_0, bb0, hist1_1, bb1, P);
    scatter1_kernel<<<dim3(P, 2), 256, 0, stream>>>(src0, dst0, hist1_0, binned0,
                                                    src1, dst1, hist1_1, binned1, E0, E1, nb, P);
    place_kernel<<<dim3(nb, 2), 256, 0, stream>>>(binned0, bb0, rp0, csr0,
                                                  binned1, bb1, rp1, csr1, N, nb);

    // G1 = x @ [Wl1;Wr1;Ws].T  (fp32 A path, NC=384)
    mfma_gemm<true><<<mB * 3, 256, 0, stream>>>(x, wc1, nullptr, G1, N, 384, mB);
    // h1 = mean_nbr0(G1L) + G1M + bl1
    agg1_kernel<<<gAgg, 256, 0, stream>>>(G1, csr0, rp0, bl1, h1h, N);
    // G2 = h1 @ [Wl2;Wr2].T  (NC=256)
    mfma_gemm<false><<<mB * 2, 256, 0, stream>>>(h1h, wc2, nullptr, G2, N, 256, mB);
    // h3 = mean_nbr1(G2L) + G2R + G1R + bl2 + bs
    agg2_kernel<<<gAgg, 256, 0, stream>>>(G2, G1, csr1, rp1, bl2, bsk, h3h, N);
    // out = relu(h3@W1.T + b1) @ W2.T + b2   (h4 in registers)
    gemm_out_kernel<<<mB, 256, 0, stream>>>(h3h, w1h, b1, W2, b2, out, N);
}

// Round 7
// 257.612 us; speedup vs baseline: 4.0537x; 1.1420x over previous
//
#include <hip/hip_runtime.h>
#include <hip/hip_bf16.h>

// GraphSAGE net on MI355X — linearity-restructured + barrier-free streaming GEMMs.
//   G1 = x @ [Wl1;Wr1;Ws].T   (fp32 A loaded direct-to-register, NC=384)
//   h1 = mean_nbr0(G1L) + G1M + bl1
//   G2 = h1 @ [Wl2;Wr2].T     (NC=256)
//   h3 = mean_nbr1(G2L) + G2R + G1R + bl2 + bs
//   out = relu(h3@W1.T+b1) @ W2.T + b2   (h4 never leaves registers)
// GEMM structure (r6 lesson: block-serial stage->barrier->MFMA was latency-bound,
// MfmaUtil 3.7%): weights staged ONCE per block in frag-swizzled LDS (conflict-free
// ds_read_b128), A-frags global->register, zero barriers in the tile loop.
// CSR build = zero-global-atomic partitioned counting sort (r3: same-address device
// atomics ~85ns; r4: spread device atomics ~32B fabric RMW each).

#define DD 128
#define SB 8               // 256 nodes per bucket
#define CH 4096            // edges per partition chunk
typedef unsigned short u16;
typedef __attribute__((ext_vector_type(8))) short short8;
typedef __attribute__((ext_vector_type(4))) float f32x4;

__device__ inline u16 f2bf(float f) {
    __hip_bfloat16 h = __float2bfloat16(f);
    u16 u;
    __builtin_memcpy(&u, &h, 2);
    return u;
}
__device__ inline unsigned pack2(float lo, float hi) {
    return (unsigned)f2bf(lo) | ((unsigned)f2bf(hi) << 16);
}
__device__ inline float bf_lo(unsigned u) { union { unsigned x; float f; } c; c.x = u << 16; return c.f; }
__device__ inline float bf_hi(unsigned u) { union { unsigned x; float f; } c; c.x = u & 0xffff0000u; return c.f; }

// ---------------- weight cast fp32 -> bf16 (concat slots) ----------------
struct CastJobs {
    const float4* src[6];
    uint2* dst[6];
    int qstart[7];
};
__global__ __launch_bounds__(256) void cast_kernel(CastJobs jb) {
    int q = blockIdx.x * 256 + threadIdx.x;
    if (q >= jb.qstart[6]) return;
    int i = 0;
#pragma unroll
    for (int k = 1; k < 6; ++k) if (q >= jb.qstart[k]) i = k;
    int local = q - jb.qstart[i];
    float4 v = jb.src[i][local];
    jb.dst[i][local] = make_uint2(pack2(v.x, v.y), pack2(v.z, v.w));
}

// ---------------- CSR build ----------------
// hist1: per-(bucket,partition) counts via LDS histogram. grid (P, 2).
__global__ __launch_bounds__(256) void hist1_kernel(const int* __restrict__ dst0, int* __restrict__ h0,
                                                    const int* __restrict__ dst1, int* __restrict__ h1,
                                                    int e0, int e1, int nb, int P) {
    int arr = blockIdx.y;
    const int* dst = arr ? dst1 : dst0;
    int* hist = arr ? h1 : h0;
    int e = arr ? e1 : e0;
    __shared__ int h[256];
    int t = threadIdx.x;
    h[t] = 0;
    __syncthreads();
    int base = blockIdx.x * CH;
    int hi = min(base + CH, e);
    for (int i = base + t; i < hi; i += 256) atomicAdd(&h[dst[i] >> SB], 1);
    __syncthreads();
    if (t < nb) hist[t * P + blockIdx.x] = h[t];   // [bucket][partition]
}

// rowsum: bucket totals = sum_p hist1[b][p], parallel per bucket. grid (nb, 2).
__global__ __launch_bounds__(256) void rowsum_kernel(const int* __restrict__ h0, int* __restrict__ bs0,
                                                     const int* __restrict__ h1, int* __restrict__ bs1,
                                                     int P) {
    int arr = blockIdx.y;
    const int* hist = arr ? h1 : h0;
    int* bs = arr ? bs1 : bs0;
    int b = blockIdx.x;
    __shared__ int s[256];
    int t = threadIdx.x;
    s[t] = (t < P) ? hist[b * P + t] : 0;
    __syncthreads();
    for (int off = 128; off; off >>= 1) {
        if (t < off) s[t] += s[t + off];
        __syncthreads();
    }
    if (t == 0) bs[b] = s[0];
}

// bscan: exclusive scan of bucket totals -> bbase; rp[n]=E. grid(2).
__global__ __launch_bounds__(256) void bscan_kernel(const int* __restrict__ bs0, int* __restrict__ bb0, int* __restrict__ rp0, int e0,
                                                    const int* __restrict__ bs1, int* __restrict__ bb1, int* __restrict__ rp1, int e1,
                                                    int nb, int n) {
    int arr = blockIdx.x;
    const int* bsum = arr ? bs1 : bs0;
    int* bb = arr ? bb1 : bb0;
    int* rp = arr ? rp1 : rp0;
    int E = arr ? e1 : e0;
    __shared__ int s[256];
    int t = threadIdx.x;
    int v = (t < nb) ? bsum[t] : 0;
    s[t] = v;
    __syncthreads();
    for (int off = 1; off < 256; off <<= 1) {
        int u = (t >= off) ? s[t - off] : 0;
        __syncthreads();
        s[t] += u;
        __syncthreads();
    }
    if (t < nb) bb[t] = s[t] - v;
    if (t == 0) { bb[nb] = E; rp[n] = E; }
}

// offs: exclusive scan over partitions per bucket, + bbase[b]. In-place. grid (nb, 2).
__global__ __launch_bounds__(256) void offs_kernel(int* __restrict__ h0, const int* __restrict__ bb0,
                                                   int* __restrict__ h1, const int* __restrict__ bb1,
                                                   int P) {
    int arr = blockIdx.y;
    int* hist = arr ? h1 : h0;
    const int* bb = arr ? bb1 : bb0;
    int b = blockIdx.x;
    __shared__ int s[256];
    int t = threadIdx.x;
    int v = (t < P) ? hist[b * P + t] : 0;
    s[t] = v;
    __syncthreads();
    for (int off = 1; off < 256; off <<= 1) {
        int u = (t >= off) ? s[t - off] : 0;
        __syncthreads();
        s[t] += u;
        __syncthreads();
    }
    if (t < P) hist[b * P + t] = s[t] - v + bb[b];
}

// scatter1: chunk p -> bucket-contiguous binned via LDS bump counters, plain stores. grid (P, 2).
__global__ __launch_bounds__(256) void scatter1_kernel(
    const int* __restrict__ src0, const int* __restrict__ dst0, const int* __restrict__ h0, unsigned* __restrict__ binned0,
    const int* __restrict__ src1, const int* __restrict__ dst1, const int* __restrict__ h1, unsigned* __restrict__ binned1,
    int e0, int e1, int nb, int P) {
    int arr = blockIdx.y;
    const int* src = arr ? src1 : src0;
    const int* dst = arr ? dst1 : dst0;
    const int* hist = arr ? h1 : h0;
    unsigned* binned = arr ? binned1 : binned0;
    int e = arr ? e1 : e0;
    int p = blockIdx.x;
    __shared__ int cnt[256];
    int t = threadIdx.x;
    if (t < nb) cnt[t] = hist[t * P + p];
    __syncthreads();
    int base = p * CH;
    int hi = min(base + CH, e);
    for (int i = base + t; i < hi; i += 256) {
        int d = dst[i];
        int pos = atomicAdd(&cnt[d >> SB], 1);        // LDS atomic
        binned[pos] = ((unsigned)d << 16) | (unsigned)src[i];
    }
}

// place: per bucket: LDS node histogram + local scan -> rp[node] and dense u16 CSR. grid (nb, 2).
__global__ __launch_bounds__(256) void place_kernel(
    const unsigned* __restrict__ binned0, const int* __restrict__ bb0, int* __restrict__ rp0, u16* __restrict__ csr0,
    const unsigned* __restrict__ binned1, const int* __restrict__ bb1, int* __restrict__ rp1, u16* __restrict__ csr1,
    int n, int nb) {
    int arr = blockIdx.y;
    const unsigned* binned = arr ? binned1 : binned0;
    const int* bb = arr ? bb1 : bb0;
    int* rp = arr ? rp1 : rp0;
    u16* csr = arr ? csr1 : csr0;
    int b = blockIdx.x;
    __shared__ int cnt[256];
    __shared__ int s[256];
    int t = threadIdx.x;
    int base = bb[b], end = bb[b + 1];
    cnt[t] = 0;
    __syncthreads();
    for (int i = base + t; i < end; i += 256)
        atomicAdd(&cnt[(binned[i] >> 16) & 255], 1);   // LDS atomic
    __syncthreads();
    int deg = cnt[t];
    s[t] = deg;
    __syncthreads();
    for (int off = 1; off < 256; off <<= 1) {
        int u = (t >= off) ? s[t - off] : 0;
        __syncthreads();
        s[t] += u;
        __syncthreads();
    }
    int gpos = base + s[t] - deg;
    int node = (b << SB) + t;
    if (node < n) rp[node] = gpos;
    cnt[t] = gpos;
    __syncthreads();
    for (int i = base + t; i < end; i += 256) {
        unsigned pk = binned[i];
        int ld = (pk >> 16) & 255;
        int pos = atomicAdd(&cnt[ld], 1);              // LDS atomic
        csr[pos] = (u16)(pk & 0xffffu);
    }
}

// ---------------- agg layer 1: h1 = mean_nbr(G1[:, :128]) + G1[:,128:256] + bl1 ----------------
// 16 lanes per node; G1 row = 48 uint4 (384 bf16). 4-way unrolled gather.
__global__ __launch_bounds__(256) void agg1_kernel(const u16* __restrict__ G1,
                                                   const u16* __restrict__ csr,
                                                   const int* __restrict__ rp,
                                                   const float* __restrict__ bl1,
                                                   u16* __restrict__ h1, int n) {
    int g = (blockIdx.x * 256 + threadIdx.x) >> 4;
    int lane = threadIdx.x & 15;
    if (g >= n) return;
    int start = rp[g], end = rp[g + 1];
    int d = end - start;
    const uint4* X4 = (const uint4*)G1;
    float acc[8] = {0.f, 0.f, 0.f, 0.f, 0.f, 0.f, 0.f, 0.f};
    int e = start;
    for (; e + 3 < end; e += 4) {
        int s0 = csr[e], s1 = csr[e + 1], s2 = csr[e + 2], s3 = csr[e + 3];
        uint4 v0 = X4[(size_t)s0 * 48 + lane];
        uint4 v1 = X4[(size_t)s1 * 48 + lane];
        uint4 v2 = X4[(size_t)s2 * 48 + lane];
        uint4 v3 = X4[(size_t)s3 * 48 + lane];
        acc[0] += (bf_lo(v0.x) + bf_lo(v1.x)) + (bf_lo(v2.x) + bf_lo(v3.x));
        acc[1] += (bf_hi(v0.x) + bf_hi(v1.x)) + (bf_hi(v2.x) + bf_hi(v3.x));
        acc[2] += (bf_lo(v0.y) + bf_lo(v1.y)) + (bf_lo(v2.y) + bf_lo(v3.y));
        acc[3] += (bf_hi(v0.y) + bf_hi(v1.y)) + (bf_hi(v2.y) + bf_hi(v3.y));
        acc[4] += (bf_lo(v0.z) + bf_lo(v1.z)) + (bf_lo(v2.z) + bf_lo(v3.z));
        acc[5] += (bf_hi(v0.z) + bf_hi(v1.z)) + (bf_hi(v2.z) + bf_hi(v3.z));
        acc[6] += (bf_lo(v0.w) + bf_lo(v1.w)) + (bf_lo(v2.w) + bf_lo(v3.w));
        acc[7] += (bf_hi(v0.w) + bf_hi(v1.w)) + (bf_hi(v2.w) + bf_hi(v3.w));
    }
    for (; e < end; ++e) {
        uint4 v0 = X4[(size_t)csr[e] * 48 + lane];
        acc[0] += bf_lo(v0.x); acc[1] += bf_hi(v0.x);
        acc[2] += bf_lo(v0.y); acc[3] += bf_hi(v0.y);
        acc[4] += bf_lo(v0.z); acc[5] += bf_hi(v0.z);
        acc[6] += bf_lo(v0.w); acc[7] += bf_hi(v0.w);
    }
    float sc = 1.0f / (float)max(d, 1);
    uint4 m = X4[(size_t)g * 48 + 16 + lane];          // G1M (x@Wr1.T)
    const float4* bl = (const float4*)bl1;
    float4 ba = bl[lane * 2], bb = bl[lane * 2 + 1];
    uint4 r;
    r.x = pack2(acc[0] * sc + bf_lo(m.x) + ba.x, acc[1] * sc + bf_hi(m.x) + ba.y);
    r.y = pack2(acc[2] * sc + bf_lo(m.y) + ba.z, acc[3] * sc + bf_hi(m.y) + ba.w);
    r.z = pack2(acc[4] * sc + bf_lo(m.z) + bb.x, acc[5] * sc + bf_hi(m.z) + bb.y);
    r.w = pack2(acc[6] * sc + bf_lo(m.w) + bb.z, acc[7] * sc + bf_hi(m.w) + bb.w);
    ((uint4*)h1)[(size_t)g * 16 + lane] = r;
}

// ---------------- agg layer 2: h3 = mean_nbr(G2L) + G2R + G1R + bl2 + bs ----------------
__global__ __launch_bounds__(256) void agg2_kernel(const u16* __restrict__ G2,
                                                   const u16* __restrict__ G1,
                                                   const u16* __restrict__ csr,
                                                   const int* __restrict__ rp,
                                                   const float* __restrict__ bl2,
                                                   const float* __restrict__ bs,
                                                   u16* __restrict__ h3, int n) {
    int g = (blockIdx.x * 256 + threadIdx.x) >> 4;
    int lane = threadIdx.x & 15;
    if (g >= n) return;
    int start = rp[g], end = rp[g + 1];
    int d = end - start;
    const uint4* X4 = (const uint4*)G2;
    float acc[8] = {0.f, 0.f, 0.f, 0.f, 0.f, 0.f, 0.f, 0.f};
    int e = start;
    for (; e + 3 < end; e += 4) {
        int s0 = csr[e], s1 = csr[e + 1], s2 = csr[e + 2], s3 = csr[e + 3];
        uint4 v0 = X4[(size_t)s0 * 32 + lane];
        uint4 v1 = X4[(size_t)s1 * 32 + lane];
        uint4 v2 = X4[(size_t)s2 * 32 + lane];
        uint4 v3 = X4[(size_t)s3 * 32 + lane];
        acc[0] += (bf_lo(v0.x) + bf_lo(v1.x)) + (bf_lo(v2.x) + bf_lo(v3.x));
        acc[1] += (bf_hi(v0.x) + bf_hi(v1.x)) + (bf_hi(v2.x) + bf_hi(v3.x));
        acc[2] += (bf_lo(v0.y) + bf_lo(v1.y)) + (bf_lo(v2.y) + bf_lo(v3.y));
        acc[3] += (bf_hi(v0.y) + bf_hi(v1.y)) + (bf_hi(v2.y) + bf_hi(v3.y));
        acc[4] += (bf_lo(v0.z) + bf_lo(v1.z)) + (bf_lo(v2.z) + bf_lo(v3.z));
        acc[5] += (bf_hi(v0.z) + bf_hi(v1.z)) + (bf_hi(v2.z) + bf_hi(v3.z));
        acc[6] += (bf_lo(v0.w) + bf_lo(v1.w)) + (bf_lo(v2.w) + bf_lo(v3.w));
        acc[7] += (bf_hi(v0.w) + bf_hi(v1.w)) + (bf_hi(v2.w) + bf_hi(v3.w));
    }
    for (; e < end; ++e) {
        uint4 v0 = X4[(size_t)csr[e] * 32 + lane];
        acc[0] += bf_lo(v0.x); acc[1] += bf_hi(v0.x);
        acc[2] += bf_lo(v0.y); acc[3] += bf_hi(v0.y);
        acc[4] += bf_lo(v0.z); acc[5] += bf_hi(v0.z);
        acc[6] += bf_lo(v0.w); acc[7] += bf_hi(v0.w);
    }
    float sc = 1.0f / (float)max(d, 1);
    uint4 m2 = X4[(size_t)g * 32 + 16 + lane];                    // G2R (h1@Wr2.T)
    uint4 m1 = ((const uint4*)G1)[(size_t)g * 48 + 32 + lane];    // G1R (x@Ws.T)
    const float4* c2 = (const float4*)bl2;
    const float4* cs = (const float4*)bs;
    float4 ba = c2[lane * 2], bb = c2[lane * 2 + 1];
    float4 sa = cs[lane * 2], sb = cs[lane * 2 + 1];
    uint4 r;
    r.x = pack2(acc[0] * sc + bf_lo(m2.x) + bf_lo(m1.x) + ba.x + sa.x,
                acc[1] * sc + bf_hi(m2.x) + bf_hi(m1.x) + ba.y + sa.y);
    r.y = pack2(acc[2] * sc + bf_lo(m2.y) + bf_lo(m1.y) + ba.z + sa.z,
                acc[3] * sc + bf_hi(m2.y) + bf_hi(m1.y) + ba.w + sa.w);
    r.z = pack2(acc[4] * sc + bf_lo(m2.z) + bf_lo(m1.z) + bb.x + sb.x,
                acc[5] * sc + bf_hi(m2.z) + bf_hi(m1.z) + bb.y + sb.y);
    r.w = pack2(acc[6] * sc + bf_lo(m2.w) + bf_lo(m1.w) + bb.z + sb.z,
                acc[7] * sc + bf_hi(m2.w) + bf_hi(m1.w) + bb.w + sb.w);
    ((uint4*)h3)[(size_t)g * 16 + lane] = r;
}

// ---------------- streaming MFMA GEMM: C = A @ W.T, bf16 out ----------------
// W tile (128 cols x K=128) staged ONCE per block in frag-swizzled LDS
// ([frag][lane][8] -> hot-loop ds_read_b128 conflict-free). A-frags load
// global->register. Zero barriers in the tile loop; each wave streams 16-row
// tiles independently. grid (blocksPerCol, NC/128). Requires M % 16 == 0.
template <bool F32A>
__global__ __launch_bounds__(256) void mfma_gemm(const void* __restrict__ Av,
                                                 const u16* __restrict__ W,
                                                 u16* __restrict__ C, int M, int NC) {
    __shared__ u16 Bs[32 * 512];   // 32 frags x 64 lanes x 8 shorts = 32 KB
    const int t = threadIdx.x;
    const int colBase = blockIdx.y * 128;
#pragma unroll
    for (int i = 0; i < 8; ++i) {               // stage 128x128 W tile, swizzled
        int id = t + 256 * i;                   // 0..2047
        int nrow = id >> 4, cc = id & 15;       // W row (col of C), k-chunk
        int f = ((nrow >> 4) << 2) | (cc >> 2); // frag = ct*4 + kk
        int dl = ((cc & 3) << 4) | (nrow & 15); // lane = half*16 + r
        *(uint4*)&Bs[(f * 64 + dl) * 8] = ((const uint4*)W)[(size_t)(colBase + nrow) * 16 + cc];
    }
    __syncthreads();
    const int w = t >> 6, lane = t & 63, r = lane & 15, half = lane >> 4;
    const int nTiles = M >> 4;
    const int nWaves = gridDim.x * 4;
    const u16* bB = &Bs[lane * 8];
    for (int tile = blockIdx.x * 4 + w; tile < nTiles; tile += nWaves) {
        int rowA = (tile << 4) + r;
        short8 af[4];
        if (F32A) {
            const float4* Arow = (const float4*)Av + (size_t)rowA * 32 + half * 2;
#pragma unroll
            for (int kk = 0; kk < 4; ++kk) {
                float4 a = Arow[kk * 8], b = Arow[kk * 8 + 1];
                uint4 v = make_uint4(pack2(a.x, a.y), pack2(a.z, a.w),
                                     pack2(b.x, b.y), pack2(b.z, b.w));
                af[kk] = *(short8*)&v;
            }
        } else {
            const uint4* Arow = (const uint4*)Av + (size_t)rowA * 16 + half;
#pragma unroll
            for (int kk = 0; kk < 4; ++kk) {
                uint4 v = Arow[kk * 4];
                af[kk] = *(short8*)&v;
            }
        }
        f32x4 acc[8];
#pragma unroll
        for (int i = 0; i < 8; ++i) acc[i] = (f32x4){0.f, 0.f, 0.f, 0.f};
#pragma unroll
        for (int kk = 0; kk < 4; ++kk)
#pragma unroll
            for (int ct = 0; ct < 8; ++ct) {
                short8 bf = *(const short8*)(bB + (ct * 4 + kk) * 512);
                acc[ct] = __builtin_amdgcn_mfma_f32_16x16x32_bf16(af[kk], bf, acc[ct], 0, 0, 0);
            }
#pragma unroll
        for (int ct = 0; ct < 8; ++ct) {
            int col = colBase + ct * 16 + r;
#pragma unroll
            for (int reg = 0; reg < 4; ++reg) {
                int row = (tile << 4) + half * 4 + reg;
                C[(size_t)row * NC + col] = f2bf(acc[ct][reg]);
            }
        }
    }
}

// ---------------- fused MLP head: out = relu(h3@W1.T + b1) @ W2.T + b2 ----------------
// Streaming, W1 (256x128) staged once frag-swizzled (64 KB); h4 in registers.
__global__ __launch_bounds__(256) void gemm_out_kernel(const u16* __restrict__ h3,
                                                       const u16* __restrict__ W1,
                                                       const float* __restrict__ b1,
                                                       const float* __restrict__ W2,
                                                       const float* __restrict__ b2,
                                                       float* __restrict__ out, int M) {
    __shared__ u16 Bs[64 * 512];   // 64 frags x 64 lanes x 8 shorts = 64 KB
    __shared__ float w2s[3 * 256];
    __shared__ float b1s[256];
    const int t = threadIdx.x;
#pragma unroll
    for (int i = 0; i < 16; ++i) {
        int id = t + 256 * i;                   // 0..4095
        int nrow = id >> 4, cc = id & 15;
        int f = ((nrow >> 4) << 2) | (cc >> 2);
        int dl = ((cc & 3) << 4) | (nrow & 15);
        *(uint4*)&Bs[(f * 64 + dl) * 8] = ((const uint4*)W1)[(size_t)nrow * 16 + cc];
    }
    for (int i = t; i < 768; i += 256) w2s[i] = W2[i];
    b1s[t] = b1[t];
    __syncthreads();
    const int w = t >> 6, lane = t & 63, r = lane & 15, half = lane >> 4;
    const int nTiles = M >> 4;
    const int nWaves = gridDim.x * 4;
    const u16* bB = &Bs[lane * 8];
    float c0 = b2[0], c1 = b2[1], c2 = b2[2];
    for (int tile = blockIdx.x * 4 + w; tile < nTiles; tile += nWaves) {
        int rowA = (tile << 4) + r;
        const uint4* Arow = (const uint4*)h3 + (size_t)rowA * 16 + half;
        short8 af[4];
#pragma unroll
        for (int kk = 0; kk < 4; ++kk) {
            uint4 v = Arow[kk * 4];
            af[kk] = *(short8*)&v;
        }
        f32x4 acc[16];
#pragma unroll
        for (int i = 0; i < 16; ++i) acc[i] = (f32x4){0.f, 0.f, 0.f, 0.f};
#pragma unroll
        for (int kk = 0; kk < 4; ++kk)
#pragma unroll
            for (int ct = 0; ct < 16; ++ct) {
                short8 bf = *(const short8*)(bB + (ct * 4 + kk) * 512);
                acc[ct] = __builtin_amdgcn_mfma_f32_16x16x32_bf16(af[kk], bf, acc[ct], 0, 0, 0);
            }
        float p[4][3] = {{0.f, 0.f, 0.f}, {0.f, 0.f, 0.f}, {0.f, 0.f, 0.f}, {0.f, 0.f, 0.f}};
#pragma unroll
        for (int ct = 0; ct < 16; ++ct) {
            int col = ct * 16 + r;
            float bv = b1s[col];
            float w0 = w2s[col], w1 = w2s[256 + col], w2v = w2s[512 + col];
#pragma unroll
            for (int reg = 0; reg < 4; ++reg) {
                float h4 = fmaxf(acc[ct][reg] + bv, 0.f);
                p[reg][0] += h4 * w0;
                p[reg][1] += h4 * w1;
                p[reg][2] += h4 * w2v;
            }
        }
#pragma unroll
        for (int m = 1; m < 16; m <<= 1)
#pragma unroll
            for (int reg = 0; reg < 4; ++reg) {
                p[reg][0] += __shfl_xor(p[reg][0], m);
                p[reg][1] += __shfl_xor(p[reg][1], m);
                p[reg][2] += __shfl_xor(p[reg][2], m);
            }
        if (r == 0) {
#pragma unroll
            for (int reg = 0; reg < 4; ++reg) {
                int row = (tile << 4) + half * 4 + reg;
                out[(size_t)row * 3 + 0] = p[reg][0] + c0;
                out[(size_t)row * 3 + 1] = p[reg][1] + c1;
                out[(size_t)row * 3 + 2] = p[reg][2] + c2;
            }
        }
    }
}

extern "C" void kernel_launch(void* const* d_in, const int* in_sizes, int n_in,
                              void* d_out, int out_size, void* d_ws, size_t ws_size,
                              hipStream_t stream) {
    const float* x   = (const float*)d_in[0];
    const int*   ei0 = (const int*)d_in[1];
    const int*   ei1 = (const int*)d_in[2];
    const float* Wl1 = (const float*)d_in[3];
    const float* bl1 = (const float*)d_in[4];
    const float* Wr1 = (const float*)d_in[5];
    const float* Wl2 = (const float*)d_in[6];
    const float* bl2 = (const float*)d_in[7];
    const float* Wr2 = (const float*)d_in[8];
    const float* Wsk = (const float*)d_in[9];
    const float* bsk = (const float*)d_in[10];
    const float* W1  = (const float*)d_in[11];
    const float* b1  = (const float*)d_in[12];
    const float* W2  = (const float*)d_in[13];
    const float* b2  = (const float*)d_in[14];
    float* out = (float*)d_out;

    const int N  = in_sizes[0] / DD;   // 50000
    const int E0 = in_sizes[1] / 2;    // 800000
    const int E1 = in_sizes[2] / 2;
    const int H  = in_sizes[12];       // 256

    const int* src0 = ei0;      const int* dst0 = ei0 + E0;
    const int* src1 = ei1;      const int* dst1 = ei1 + E1;

    const int nb   = (N + 255) >> SB;                  // 196 buckets
    const int Emax = (E0 > E1) ? E0 : E1;
    const int P    = (Emax + CH - 1) / CH;             // 196 partitions (<= 256)

    // workspace carve (256B aligned)
    char* wp = (char*)d_ws;
    auto carve = [&](size_t bytes) { char* p = wp; wp += (bytes + 255) & ~(size_t)255; return p; };
    u16* G1   = (u16*)carve((size_t)N * 384 * 2);
    u16* G2   = (u16*)carve((size_t)N * 256 * 2);
    u16* h1h  = (u16*)carve((size_t)N * DD * 2);
    u16* h3h  = (u16*)carve((size_t)N * DD * 2);
    u16* wc1  = (u16*)carve((size_t)384 * DD * 2);   // [Wl1;Wr1;Ws]
    u16* wc2  = (u16*)carve((size_t)256 * DD * 2);   // [Wl2;Wr2]
    u16* w1h  = (u16*)carve((size_t)H * DD * 2);
    int* rp0  = (int*)carve((size_t)(N + 1) * 4);
    int* rp1  = (int*)carve((size_t)(N + 1) * 4);
    u16* csr0 = (u16*)carve((size_t)E0 * 2);
    u16* csr1 = (u16*)carve((size_t)E1 * 2);
    unsigned* binned0 = (unsigned*)carve((size_t)E0 * 4);
    unsigned* binned1 = (unsigned*)carve((size_t)E1 * 4);
    int* hist1_0 = (int*)carve((size_t)nb * P * 4);
    int* hist1_1 = (int*)carve((size_t)nb * P * 4);
    int* bsum0 = (int*)carve((size_t)nb * 4);
    int* bsum1 = (int*)carve((size_t)nb * 4);
    int* bb0 = (int*)carve((size_t)(nb + 1) * 4);
    int* bb1 = (int*)carve((size_t)(nb + 1) * 4);

    // weight cast into concat slots
    CastJobs jb;
    const float* srcs[6] = {Wl1, Wr1, Wsk, Wl2, Wr2, W1};
    u16* dsts[6] = {wc1, wc1 + 128 * DD, wc1 + 256 * DD, wc2, wc2 + 128 * DD, w1h};
    int  cnts[6] = {DD * DD, DD * DD, DD * DD, DD * DD, DD * DD, H * DD};
    int q = 0;
    for (int i = 0; i < 6; ++i) {
        jb.src[i] = (const float4*)srcs[i];
        jb.dst[i] = (uint2*)dsts[i];
        jb.qstart[i] = q;
        q += cnts[i] / 4;
    }
    jb.qstart[6] = q;

    const int gAgg = (N * 16 + 255) / 256;

    cast_kernel<<<(q + 255) / 256, 256, 0, stream>>>(jb);
    hist1_kernel<<<dim3(P, 2), 256, 0, stream>>>(dst0, hist1_0, dst1, hist1_1, E0, E1, nb, P);
    rowsum_kernel<<<dim3(nb, 2), 256, 0, stream>>>(hist1_0, bsum0, hist1_1, bsum1, P);
    bscan_kernel<<<2, 256, 0, stream>>>(bsum0, bb0, rp0, E0, bsum1, bb1, rp1, E1, nb, N);
    offs_kernel<<<dim3(nb, 2), 256, 0, stream>>>(hist1_0, bb0, hist1_1, bb1, P);
    scatter1_kernel<<<dim3(P, 2), 256, 0, stream>>>(src0, dst0, hist1_0, binned0,
                                                    src1, dst1, hist1_1, binned1, E0, E1, nb, P);
    place_kernel<<<dim3(nb, 2), 256, 0, stream>>>(binned0, bb0, rp0, csr0,
                                                  binned1, bb1, rp1, csr1, N, nb);

    // G1 = x @ [Wl1;Wr1;Ws].T  (fp32 A direct-to-register, NC=384)
    mfma_gemm<true><<<dim3(320, 3), 256, 0, stream>>>(x, wc1, G1, N, 384);
    // h1 = mean_nbr0(G1L) + G1M + bl1
    agg1_kernel<<<gAgg, 256, 0, stream>>>(G1, csr0, rp0, bl1, h1h, N);
    // G2 = h1 @ [Wl2;Wr2].T  (NC=256)
    mfma_gemm<false><<<dim3(320, 2), 256, 0, stream>>>(h1h, wc2, G2, N, 256);
    // h3 = mean_nbr1(G2L) + G2R + G1R + bl2 + bs
    agg2_kernel<<<gAgg, 256, 0, stream>>>(G2, G1, csr1, rp1, bl2, bsk, h3h, N);
    // out = relu(h3@W1.T + b1) @ W2.T + b2   (h4 in registers)
    gemm_out_kernel<<<512, 256, 0, stream>>>(h3h, w1h, b1, W2, b2, out, N);
}